// Round 9
// baseline (1339.695 us; speedup 1.0000x reference)
//
#include <hip/hip_runtime.h>
#include <hip/hip_bf16.h>
#include <math.h>

// Model_45904610459674: FEDformer-style forecaster.
// Round 18: R17 (1310 us, best) + ONE lever: gemm_bb's bf16 epilogue was
// per-lane 2-byte scatter stores -> ~2x write amplification (WRITE_SIZE
// 96 MB vs 50 MB logical on the FFN gemms, 2.7 TB/s write-limited).
// Now the 128x128 bf16 tile is staged through LDS (pitch 136, 16B-aligned
// rows) and stored as block-wide uint4 runs — full 64B sectors. LDS grows
// 32->34.8 KB (still 4 blocks/CU). Bit-identical values, store order only.
// Everything else byte-identical to R17.
// Workspace: 53,768,192 floats = 215.07 MB (same guard).

#define PI_F 3.14159265358979323846f

typedef short bf16x8 __attribute__((ext_vector_type(8)));
typedef float f32x4 __attribute__((ext_vector_type(4)));

static __device__ __forceinline__ int iclamp(int v, int lo, int hi) {
    return v < lo ? lo : (v > hi ? hi : v);
}
static __device__ __forceinline__ unsigned pack2(float x, float y) {
    unsigned xu = __float_as_uint(x) + 0x8000u;
    unsigned yu = __float_as_uint(y) + 0x8000u;
    return (xu >> 16) | (yu & 0xFFFF0000u);
}
static __device__ __forceinline__ unsigned short bfr(float x) {
    return (unsigned short)((__float_as_uint(x) + 0x8000u) >> 16);
}
static __device__ __forceinline__ float bf2f(unsigned short s) {
    return __uint_as_float((unsigned)s << 16);
}

__global__ void zero_out_kernel(float* __restrict__ out, int n) {
    int i = blockIdx.x * 256 + threadIdx.x;
    if (i < n) out[i] = 0.f;
}

// fused fp32->bf16 for all 11 weight tensors in one dispatch.
// Sizes are all multiples of 1024, so each block does exactly 1024 elems.
struct F2BArgs {
    const float* s[11];
    unsigned short* d[11];
    int boff[12];
};
__global__ void f2b_multi(F2BArgs a) {
    int blk = blockIdx.x;
    int seg = 0;
    while (blk >= a.boff[seg + 1]) seg++;  // uniform scalar scan, <=11 iters
    int i = (blk - a.boff[seg]) * 1024 + threadIdx.x * 4;
    const float4 v = *(const float4*)(a.s[seg] + i);
    *(uint2*)(a.d[seg] + i) = make_uint2(pack2(v.x, v.y), pack2(v.z, v.w));
}

// ---------------------------------------------------------------------------
__global__ void preprocess_kernel(const float* __restrict__ xe,
                                  float* __restrict__ SI, float* __restrict__ TI) {
    int idx = blockIdx.x * 256 + threadIdx.x;
    if (idx >= 128 * 144 * 7) return;
    int c = idx % 7;
    int l = (idx / 7) % 144;
    int b = idx / (7 * 144);
    const float* xb = xe + (size_t)b * 96 * 7;
    if (l < 48) {
        int p = 48 + l;
        float sum = 0.f;
        for (int j = -12; j <= 12; j++) sum += xb[iclamp(p + j, 0, 95) * 7 + c];
        float ma = sum * (1.0f / 25.0f);
        SI[idx] = xb[p * 7 + c] - ma;
        TI[idx] = ma;
    } else {
        SI[idx] = 0.f;
        float m = 0.f;
        for (int l2 = 0; l2 < 96; l2++) m += xb[l2 * 7 + c];
        TI[idx] = m * (1.0f / 96.0f);
    }
}

// ---------------------------------------------------------------------------
// Embedding as GEMM: feature matrix F[row][k] bf16, K padded 25->64.
// k = c*3+t  -> x[l_t, c]  (t: 0=l-1 circ, 1=l, 2=l+1 circ)
// k = 21+f   -> mark[f];   k >= 25 -> 0
__global__ void embed_feat(const float* __restrict__ x, const float* __restrict__ mark,
                           unsigned short* __restrict__ F, int L) {
    int row = blockIdx.x * 256 + threadIdx.x;
    if (row >= 128 * L) return;
    int l = row % L;
    int b = row / L;
    int lm = (l == 0) ? L - 1 : l - 1;
    int lp = (l == L - 1) ? 0 : l + 1;
    const float* x0 = x + (size_t)b * L * 7;
    const float* mk = mark + (size_t)row * 4;
    union { unsigned short s[64]; uint4 u[8]; } f;
#pragma unroll
    for (int k = 0; k < 8; k++) f.u[k] = make_uint4(0u, 0u, 0u, 0u);
#pragma unroll
    for (int c = 0; c < 7; c++) {
        f.s[c * 3 + 0] = bfr(x0[lm * 7 + c]);
        f.s[c * 3 + 1] = bfr(x0[l * 7 + c]);
        f.s[c * 3 + 2] = bfr(x0[lp * 7 + c]);
    }
#pragma unroll
    for (int j = 0; j < 4; j++) f.s[21 + j] = bfr(mk[j]);
    uint4* dst = (uint4*)(F + (size_t)row * 64);
#pragma unroll
    for (int k = 0; k < 8; k++) dst[k] = f.u[k];
}

// packed embedding weight Wc[o][k] bf16, matching embed_feat's k layout
__global__ void embed_wpack(const float* __restrict__ cw, const float* __restrict__ tw,
                            unsigned short* __restrict__ Wc) {
    int o = blockIdx.x * 256 + threadIdx.x;
    if (o >= 512) return;
    union { unsigned short s[64]; uint4 u[8]; } f;
#pragma unroll
    for (int k = 0; k < 8; k++) f.u[k] = make_uint4(0u, 0u, 0u, 0u);
#pragma unroll
    for (int c = 0; c < 7; c++) {
        const float* w = cw + (o * 7 + c) * 3;
        f.s[c * 3 + 0] = bfr(w[0]);
        f.s[c * 3 + 1] = bfr(w[1]);
        f.s[c * 3 + 2] = bfr(w[2]);
    }
#pragma unroll
    for (int j = 0; j < 4; j++) f.s[21 + j] = bfr(tw[o * 4 + j]);
    uint4* dst = (uint4*)(Wc + (size_t)o * 64);
#pragma unroll
    for (int k = 0; k < 8; k++) dst[k] = f.u[k];
}

// ---------------------------------------------------------------------------
// gemm_bb: A,W bf16. Staging: global_load_lds 16B DMA, XOR-swizzled chunks.
// Epilogue: Cf (fp32) scalar (full sectors already); Cb (bf16) staged via
// LDS tile (pitch 136) then block-wide uint4 stores — fixes the 2x write
// amplification of per-lane 2B scatters. accum reads Cf if present, else
// Cb (bf16 accumulate, one extra rounding — dec-FFN chunk sum).
__global__ __launch_bounds__(256, 4) void gemm_bb(
    const unsigned short* __restrict__ A, const unsigned short* __restrict__ W,
    const float* __restrict__ bias, float* __restrict__ Cf,
    unsigned short* __restrict__ Cb,
    int N, int K, int lda, int ldw, int gelu, int accum) {
    __shared__ unsigned short sh[128 * 136];  // 34816 B; staging uses first 32KB
    unsigned short* As = sh;
    unsigned short* Ws = sh + 8192;
    const int tid = threadIdx.x;
    const int lane = tid & 63, wv = tid >> 6;
    const int wm = (wv & 1) * 64, wn = (wv >> 1) * 64;
    const int q = lane >> 4, ln = lane & 15;
    const size_t bm = (size_t)blockIdx.y * 128;
    const size_t bn = (size_t)blockIdx.x * 128;

    f32x4 acc[4][4];
#pragma unroll
    for (int i = 0; i < 4; i++)
#pragma unroll
        for (int j = 0; j < 4; j++) acc[i][j] = (f32x4){0.f, 0.f, 0.f, 0.f};

    for (int k0 = 0; k0 < K; k0 += 64) {
#pragma unroll
        for (int t = 0; t < 4; t++) {
            int idx = (wv * 4 + t) * 64 + lane;
            int row = idx >> 3, cp = idx & 7;
            int cl = cp ^ (row & 7);
            __builtin_amdgcn_global_load_lds(
                (const __attribute__((address_space(1))) void*)(A + (bm + row) * lda + k0 + cl * 8),
                (__attribute__((address_space(3))) void*)(As + (size_t)(wv * 4 + t) * 512),
                16, 0, 0);
            __builtin_amdgcn_global_load_lds(
                (const __attribute__((address_space(1))) void*)(W + (bn + row) * ldw + k0 + cl * 8),
                (__attribute__((address_space(3))) void*)(Ws + (size_t)(wv * 4 + t) * 512),
                16, 0, 0);
        }
        __syncthreads();
#pragma unroll
        for (int kk = 0; kk < 64; kk += 32) {
            bf16x8 af[4], bfr4[4];
            const int cq = (kk >> 3) + q;
#pragma unroll
            for (int i = 0; i < 4; i++) {
                int r = wm + i * 16 + ln;
                af[i] = *(const bf16x8*)(As + r * 64 + ((cq ^ (r & 7)) * 8));
                int rw = wn + i * 16 + ln;
                bfr4[i] = *(const bf16x8*)(Ws + rw * 64 + ((cq ^ (rw & 7)) * 8));
            }
#pragma unroll
            for (int i = 0; i < 4; i++)
#pragma unroll
                for (int j = 0; j < 4; j++)
                    acc[i][j] = __builtin_amdgcn_mfma_f32_16x16x32_bf16(
                        af[i], bfr4[j], acc[i][j], 0, 0, 0);
        }
        __syncthreads();
    }
    if (Cb) {
        // stage bf16 tile in LDS (values identical to scalar path)
#pragma unroll
        for (int j = 0; j < 4; j++) {
            int col = wn + j * 16 + ln;
            int gcol = (int)bn + col;
            float bv = bias ? bias[gcol] : 0.f;
#pragma unroll
            for (int i = 0; i < 4; i++) {
                int r0 = wm + i * 16 + q * 4;
#pragma unroll
                for (int r = 0; r < 4; r++) {
                    float v = acc[i][j][r] + bv;
                    if (gelu) v = 0.5f * v * (1.f + erff(v * 0.70710678118654752f));
                    size_t off = (bm + r0 + r) * N + gcol;
                    if (Cf) {
                        float* p = Cf + off;
                        if (accum) v += *p;
                        *p = v;
                    } else if (accum) {
                        v += bf2f(Cb[off]);
                    }
                    sh[(r0 + r) * 136 + col] = bfr(v);
                }
            }
        }
        __syncthreads();
        // coalesced store: 128 rows x 256B, uint4 per lane
        for (int idx = tid; idx < 128 * 16; idx += 256) {
            int row = idx >> 4, c = idx & 15;
            uint4 v = *(const uint4*)&sh[row * 136 + c * 8];
            *(uint4*)(Cb + (bm + row) * N + bn + c * 8) = v;
        }
    } else {
#pragma unroll
        for (int j = 0; j < 4; j++) {
            int col = (int)bn + wn + j * 16 + ln;
            float bv = bias ? bias[col] : 0.f;
#pragma unroll
            for (int i = 0; i < 4; i++) {
                size_t row0 = bm + wm + i * 16 + q * 4;
#pragma unroll
                for (int r = 0; r < 4; r++) {
                    float v = acc[i][j][r] + bv;
                    if (gelu) v = 0.5f * v * (1.f + erff(v * 0.70710678118654752f));
                    float* p = Cf + (row0 + r) * N + col;
                    if (accum) v += *p;
                    *p = v;
                }
            }
        }
    }
}

// ---------------------------------------------------------------------------
// twiddle tables (bf16)
__global__ void dtab_kernel(unsigned short* __restrict__ T, int M, int L, int ldk) {
    int i = blockIdx.x * 256 + threadIdx.x;
    if (i >= 128 * ldk) return;
    int n = i / ldk, k = i - n * ldk;
    float val = 0.f;
    if (n < 2 * M && k < L) {
        int m = n >> 1;
        int r = (m * k) % L;
        float ang = -2.f * PI_F * (float)r / (float)L;
        val = (n & 1) ? sinf(ang) : cosf(ang);
    }
    T[i] = bfr(val);
}
__global__ void itab_kernel(unsigned short* __restrict__ T, int M, int L, int K) {
    int i = blockIdx.x * 256 + threadIdx.x;
    if (i >= L * K) return;
    int n = i / K, k = i - n * K;
    int m = k >> 1;
    float c = (m == 0) ? 1.f : 2.f;
    int r = (m * n) % L;
    float ang = 2.f * PI_F * (float)r / (float)L;
    float val = (k & 1) ? -c * sinf(ang) : c * cosf(ang);
    T[i] = bfr(val);
}

// ---------------------------------------------------------------------------
// dft MFMA v2 (bf16 input): P bf16 [B*L,512] -> XT[h][m][b][2e+p] bf16
__global__ __launch_bounds__(256) void dft_mfma2(
    const unsigned short* __restrict__ P, const unsigned short* __restrict__ Tdb,
    unsigned short* __restrict__ XT, int L, int ldk, int M) {
    __shared__ unsigned short tile[128 * 130];
    const int tid = threadIdx.x;
    const int lane = tid & 63, wv = tid >> 6;
    const int wm = (wv & 1) * 64, wn = (wv >> 1) * 64;
    const int q = lane >> 4, ln = lane & 15;
    const int bm = blockIdx.y;
    const int b = bm >> 2, c0 = (bm & 3) * 128;
    const int h0 = c0 >> 6;
    const unsigned short* Pb = P + (size_t)b * L * 512;

    f32x4 acc[4][4];
#pragma unroll
    for (int i = 0; i < 4; i++)
#pragma unroll
        for (int j = 0; j < 4; j++) acc[i][j] = (f32x4){0.f, 0.f, 0.f, 0.f};

    for (int k0 = 0; k0 < L; k0 += 32) {
        bf16x8 af[4], bf[4];
        union FR { bf16x8 v; unsigned short s[8]; };
#pragma unroll
        for (int i = 0; i < 4; i++) {
            int c = c0 + wm + i * 16 + ln;
            FR fr;
#pragma unroll
            for (int t = 0; t < 8; t++) {
                int l = k0 + q * 8 + t;
                fr.s[t] = (l < L) ? Pb[(size_t)l * 512 + c] : (unsigned short)0;
            }
            af[i] = fr.v;
        }
#pragma unroll
        for (int j = 0; j < 4; j++) {
            int n = wn + j * 16 + ln;
            bf[j] = *(const bf16x8*)(Tdb + (size_t)n * ldk + k0 + q * 8);
        }
#pragma unroll
        for (int i = 0; i < 4; i++)
#pragma unroll
            for (int j = 0; j < 4; j++)
                acc[i][j] = __builtin_amdgcn_mfma_f32_16x16x32_bf16(
                    af[i], bf[j], acc[i][j], 0, 0, 0);
    }
#pragma unroll
    for (int j = 0; j < 4; j++) {
        int col = wn + j * 16 + ln;
#pragma unroll
        for (int i = 0; i < 4; i++) {
            int r0 = wm + i * 16 + q * 4;
#pragma unroll
            for (int r = 0; r < 4; r++)
                tile[(r0 + r) * 130 + col] = bfr(acc[i][j][r]);
        }
    }
    __syncthreads();
    unsigned* XTu = (unsigned*)XT;
    for (int idx = tid; idx < 2 * M * 64; idx += 256) {
        int chunk = idx >> 6, e = idx & 63;
        int h2 = chunk / M, m = chunk - h2 * M;
        unsigned v = *(const unsigned*)&tile[(h2 * 64 + e) * 130 + 2 * m];
        XTu[((size_t)((h0 + h2) * M + m) * 128 + b) * 64 + e] = v;
    }
}

// ---------------------------------------------------------------------------
// wtrans3: w[h][e][o][m][2] fp32 -> WB[(h*M+m)][n=2o+q][k=2e+p] bf16
__global__ __launch_bounds__(256) void wtrans3(
    const float* __restrict__ w, unsigned short* __restrict__ WB, int M) {
    __shared__ float Lre[16 * 289], Lim[16 * 289];
    const int h = blockIdx.y;
    const int ot = blockIdx.x >> 1, et = blockIdx.x & 1;
    const int o0 = ot * 8, e0 = et * 32;
    const int tid = threadIdx.x;
    unsigned* WBu = (unsigned*)WB;
    for (int mc = 0; mc < M; mc += 16) {
        for (int idx = tid; idx < 4096; idx += 256) {
            int e = idx >> 7, o = (idx >> 4) & 7, mm = idx & 15;
            const float2 v = *(const float2*)(
                w + ((((size_t)h * 64 + e0 + e) * 64 + o0 + o) * M + mc + mm) * 2);
            Lre[mm * 289 + e * 9 + o] = v.x;
            Lim[mm * 289 + e * 9 + o] = v.y;
        }
        __syncthreads();
        for (int widx = tid; widx < 8192; widx += 256) {
            int mm = widx >> 9, no = (widx >> 5) & 15, e = widx & 31;
            int ol = no >> 1, qn = no & 1;
            float re = Lre[mm * 289 + e * 9 + ol];
            float im = Lim[mm * 289 + e * 9 + ol];
            unsigned v = qn ? pack2(im, re) : pack2(re, -im);
            WBu[((size_t)(h * M + mc + mm) * 128 + 2 * (o0 + ol) + qn) * 64 + e0 + e] = v;
        }
        __syncthreads();
    }
}

// ---------------------------------------------------------------------------
// mix_v2: per (h,m): Y'[b][n] = sum_k XT[hm][b][k]*WB[hm][n][k], b128 loads
__global__ __launch_bounds__(256) void mix_v2(
    const unsigned short* __restrict__ XT, const unsigned short* __restrict__ WB,
    unsigned short* __restrict__ Yp, int M) {
    __shared__ unsigned short tile[128 * 130];
    const int m = blockIdx.x, h = blockIdx.y;
    const int tid = threadIdx.x;
    const int lane = tid & 63, wv = tid >> 6;
    const int wm = (wv & 1) * 64, wn = (wv >> 1) * 64;
    const int q = lane >> 4, ln = lane & 15;
    const size_t hm = (size_t)h * M + m;
    const unsigned short* Ab = XT + hm * 16384;
    const unsigned short* Bb = WB + hm * 16384;

    f32x4 acc[4][4];
#pragma unroll
    for (int i = 0; i < 4; i++)
#pragma unroll
        for (int j = 0; j < 4; j++) acc[i][j] = (f32x4){0.f, 0.f, 0.f, 0.f};

#pragma unroll
    for (int k0 = 0; k0 < 128; k0 += 32) {
        bf16x8 af[4], bf[4];
#pragma unroll
        for (int i = 0; i < 4; i++)
            af[i] = *(const bf16x8*)(Ab + (size_t)(wm + i * 16 + ln) * 128 + k0 + q * 8);
#pragma unroll
        for (int j = 0; j < 4; j++)
            bf[j] = *(const bf16x8*)(Bb + (size_t)(wn + j * 16 + ln) * 128 + k0 + q * 8);
#pragma unroll
        for (int i = 0; i < 4; i++)
#pragma unroll
            for (int j = 0; j < 4; j++)
                acc[i][j] = __builtin_amdgcn_mfma_f32_16x16x32_bf16(
                    af[i], bf[j], acc[i][j], 0, 0, 0);
    }
#pragma unroll
    for (int j = 0; j < 4; j++) {
        int col = wn + j * 16 + ln;
#pragma unroll
        for (int i = 0; i < 4; i++) {
            int r0 = wm + i * 16 + q * 4;
#pragma unroll
            for (int r = 0; r < 4; r++)
                tile[(r0 + r) * 130 + col] = bfr(acc[i][j][r]);
        }
    }
    __syncthreads();
    unsigned* Yu = (unsigned*)Yp;
    for (int idx = tid; idx < 128 * 64; idx += 256) {
        int b = idx >> 6, dw = idx & 63;
        unsigned v = *(const unsigned*)&tile[b * 130 + 2 * dw];
        Yu[(hm * 128 + b) * 64 + dw] = v;
    }
}

// ---------------------------------------------------------------------------
// idft_v2: Out bf16 [(b,h,o)*L + l] = bf16(s * sum_k Y'[..][k]*Ti[l][k])
__global__ __launch_bounds__(256) void idft_v2(
    const unsigned short* __restrict__ Yp, const unsigned short* __restrict__ Tib,
    unsigned short* __restrict__ Out, int L, int K, int M, float s) {
    __shared__ unsigned short sh[2 * 64 * 132];
    const int tid = threadIdx.x;
    const int lane = tid & 63, wv = tid >> 6;
    const int wm = (wv & 1) * 64, wn = (wv >> 1) * 64;
    const int q = lane >> 4, ln = lane & 15;
    const int bm = blockIdx.y;
    const int b = bm >> 2, h0 = (bm & 3) * 2;
    const int bn = blockIdx.x * 128;

    const unsigned* Yu = (const unsigned*)Yp;
    for (int idx = tid; idx < 2 * M * 64; idx += 256) {
        int chunk = idx >> 6, dw = idx & 63;
        int h2 = chunk / M, m = chunk - h2 * M;
        unsigned v = Yu[((size_t)((h0 + h2) * M + m) * 128 + b) * 64 + dw];
        *(unsigned*)&sh[chunk * 132 + 2 * dw] = v;
    }
    __syncthreads();

    f32x4 acc[4][4];
#pragma unroll
    for (int i = 0; i < 4; i++)
#pragma unroll
        for (int j = 0; j < 4; j++) acc[i][j] = (f32x4){0.f, 0.f, 0.f, 0.f};

    for (int k0 = 0; k0 < K; k0 += 32) {
        bf16x8 af[4], bf[4];
        union FR { bf16x8 v; unsigned u[4]; };
#pragma unroll
        for (int i = 0; i < 4; i++) {
            int lr = wm + i * 16 + ln;
            int h2 = lr >> 6, o = lr & 63;
            FR fr;
#pragma unroll
            for (int jj = 0; jj < 4; jj++) {
                int m = (k0 >> 1) + q * 4 + jj;
                fr.u[jj] = *(const unsigned*)&sh[(h2 * M + m) * 132 + 2 * o];
            }
            af[i] = fr.v;
        }
#pragma unroll
        for (int j = 0; j < 4; j++) {
            int n = bn + wn + j * 16 + ln;
            if (n < L) bf[j] = *(const bf16x8*)(Tib + (size_t)n * K + k0 + q * 8);
            else bf[j] = (bf16x8){0, 0, 0, 0, 0, 0, 0, 0};
        }
#pragma unroll
        for (int i = 0; i < 4; i++)
#pragma unroll
            for (int j = 0; j < 4; j++)
                acc[i][j] = __builtin_amdgcn_mfma_f32_16x16x32_bf16(
                    af[i], bf[j], acc[i][j], 0, 0, 0);
    }
#pragma unroll
    for (int j = 0; j < 4; j++) {
        int col = bn + wn + j * 16 + ln;
        if (col >= L) continue;
#pragma unroll
        for (int i = 0; i < 4; i++) {
            int row0 = bm * 128 + wm + i * 16 + q * 4;
#pragma unroll
            for (int r = 0; r < 4; r++)
                Out[(size_t)(row0 + r) * L + col] = bfr(acc[i][j][r] * s);
        }
    }
}

// ---------------------------------------------------------------------------
// xqk3: per (b,h): S = Q^T [Kre|Kim] via 64x96x128 bf16 MFMA, tanh -> G.
// Qs pitch 136 (16B-aligned rows, 2-way bank alias), Bs stacked re/im.
__global__ __launch_bounds__(256) void xqk3(
    const unsigned short* __restrict__ XTQ, const unsigned short* __restrict__ XTK,
    unsigned* __restrict__ G) {
    __shared__ __align__(16) unsigned char sm[43520];
    unsigned short* Qs = (unsigned short*)sm;            // [64][136]
    unsigned short* Bs = (unsigned short*)(sm + 17408);  // [96][136]
    float* Ss = (float*)sm;                              // [64][100] alias
    const int b = blockIdx.x, h = blockIdx.y;
    const int tid = threadIdx.x;
    const int lane = tid & 63, wv = tid >> 6;
    const int wm = (wv & 1) * 32, wn = (wv >> 1) * 48;
    const int q = lane >> 4, ln = lane & 15;

    // stage Q rows (64 x 256B, contiguous per row)
    const uint4* Qg = (const uint4*)XTQ;
    for (int i = tid; i < 64 * 16; i += 256) {
        int x = i >> 4, c = i & 15;
        *(uint4*)(Qs + x * 136 + c * 8) = Qg[((size_t)(h * 64 + x) * 128 + b) * 16 + c];
    }
    // stage K -> stacked B: row y = (kr,-ki); row 48+y = (ki,kr)
    const unsigned* Ku = (const unsigned*)XTK;
    unsigned* Bu = (unsigned*)Bs;
    for (int i = tid; i < 48 * 64; i += 256) {
        int y = i >> 6, e = i & 63;
        unsigned v = Ku[((size_t)(h * 48 + y) * 128 + b) * 64 + e];
        Bu[y * 68 + e] = v ^ 0x80000000u;
        Bu[(48 + y) * 68 + e] = (v >> 16) | (v << 16);
    }
    __syncthreads();

    f32x4 acc[2][3];
#pragma unroll
    for (int i = 0; i < 2; i++)
#pragma unroll
        for (int j = 0; j < 3; j++) acc[i][j] = (f32x4){0.f, 0.f, 0.f, 0.f};

#pragma unroll
    for (int k0 = 0; k0 < 128; k0 += 32) {
        bf16x8 af[2], bf[3];
#pragma unroll
        for (int i = 0; i < 2; i++)
            af[i] = *(const bf16x8*)(Qs + (wm + i * 16 + ln) * 136 + k0 + q * 8);
#pragma unroll
        for (int j = 0; j < 3; j++)
            bf[j] = *(const bf16x8*)(Bs + (wn + j * 16 + ln) * 136 + k0 + q * 8);
#pragma unroll
        for (int i = 0; i < 2; i++)
#pragma unroll
            for (int j = 0; j < 3; j++)
                acc[i][j] = __builtin_amdgcn_mfma_f32_16x16x32_bf16(
                    af[i], bf[j], acc[i][j], 0, 0, 0);
    }
    __syncthreads();   // safe to alias Ss over Qs/Bs
#pragma unroll
    for (int j = 0; j < 3; j++) {
        int col = wn + j * 16 + ln;
#pragma unroll
        for (int i = 0; i < 2; i++) {
            int r0 = wm + i * 16 + q * 4;
#pragma unroll
            for (int r = 0; r < 4; r++)
                Ss[(r0 + r) * 100 + col] = acc[i][j][r];
        }
    }
    __syncthreads();
    for (int i = tid; i < 3072; i += 256) {
        int x = i / 48, y = i - x * 48;
        float re = Ss[x * 100 + y], im = Ss[x * 100 + 48 + y];
        float a2 = 2.f * re, b2 = 2.f * im;
        a2 = fminf(fmaxf(a2, -80.f), 80.f);
        float denom = coshf(a2) + cosf(b2);
        G[((size_t)(b * 8 + h) * 64 + x) * 48 + y] =
            pack2(sinhf(a2) / denom, sinf(b2) / denom);
    }
}

// ---------------------------------------------------------------------------
// xqkv3: per (b,h): V = G · B2 via 64x128x96 bf16 MFMA.
// A = G rows (bf16 pairs, direct global, 192B rows). B2[2e+q][2y+p] in LDS
// (pitch 104, 16B-aligned rows). Out VT[h][x][b][2e+p] via LDS restage.
__global__ __launch_bounds__(256) void xqkv3(
    const unsigned* __restrict__ G, const unsigned short* __restrict__ XTK,
    unsigned short* __restrict__ VT) {
    __shared__ __align__(16) unsigned char sm[26624];
    unsigned short* Bs = (unsigned short*)sm;   // [128][104]
    unsigned short* Vs = (unsigned short*)sm;   // [64][132] alias after MFMA
    const int b = blockIdx.x, h = blockIdx.y;
    const int tid = threadIdx.x;
    const int lane = tid & 63, wv = tid >> 6;
    const int wm = (wv & 1) * 32, wn = (wv >> 1) * 64;
    const int q = lane >> 4, ln = lane & 15;

    const unsigned* Ku = (const unsigned*)XTK;
    unsigned* Bu = (unsigned*)Bs;
    for (int i = tid; i < 48 * 64; i += 256) {
        int y = i >> 6, e = i & 63;
        unsigned v = Ku[((size_t)(h * 48 + y) * 128 + b) * 64 + e];
        Bu[(2 * e) * 52 + y] = v ^ 0x80000000u;          // (kr,-ki)
        Bu[(2 * e + 1) * 52 + y] = (v >> 16) | (v << 16); // (ki,kr)
    }
    __syncthreads();

    const unsigned short* Ag = (const unsigned short*)G + (size_t)(b * 8 + h) * 6144;
    f32x4 acc[2][4];
#pragma unroll
    for (int i = 0; i < 2; i++)
#pragma unroll
        for (int j = 0; j < 4; j++) acc[i][j] = (f32x4){0.f, 0.f, 0.f, 0.f};

#pragma unroll
    for (int k0 = 0; k0 < 96; k0 += 32) {
        bf16x8 af[2], bf[4];
#pragma unroll
        for (int i = 0; i < 2; i++)
            af[i] = *(const bf16x8*)(Ag + (wm + i * 16 + ln) * 96 + k0 + q * 8);
#pragma unroll
        for (int j = 0; j < 4; j++)
            bf[j] = *(const bf16x8*)(Bs + (wn + j * 16 + ln) * 104 + k0 + q * 8);
#pragma unroll
        for (int i = 0; i < 2; i++)
#pragma unroll
            for (int j = 0; j < 4; j++)
                acc[i][j] = __builtin_amdgcn_mfma_f32_16x16x32_bf16(
                    af[i], bf[j], acc[i][j], 0, 0, 0);
    }
    __syncthreads();   // alias Vs over Bs
#pragma unroll
    for (int j = 0; j < 4; j++) {
        int col = wn + j * 16 + ln;
#pragma unroll
        for (int i = 0; i < 2; i++) {
            int r0 = wm + i * 16 + q * 4;
#pragma unroll
            for (int r = 0; r < 4; r++)
                Vs[(r0 + r) * 132 + col] = bfr(acc[i][j][r]);
        }
    }
    __syncthreads();
    unsigned* Vu = (unsigned*)VT;
    for (int i = tid; i < 64 * 64; i += 256) {
        int x = i >> 6, dw = i & 63;
        Vu[((size_t)(h * 64 + x) * 128 + b) * 64 + dw] = *(unsigned*)&Vs[x * 132 + 2 * dw];
    }
}

// ---------------------------------------------------------------------------
// series_decomp v3: exact sliding window with inline coalesced writes.
__global__ void decomp_kernel(const float* __restrict__ P, const float* __restrict__ Q,
                              const unsigned short* __restrict__ Qb,
                              float* __restrict__ SO, unsigned short* __restrict__ SOb,
                              float* __restrict__ TS, int L, int tmode) {
    int b = blockIdx.x, d0 = blockIdx.y * 64;
    __shared__ float s[144 * 64];
    const int nvec = L * 16;  // float4 chunks (64 floats = 16 chunks per row)
    for (int i = threadIdx.x; i < nvec; i += 256) {
        int l = i >> 4, c = i & 15;
        size_t gidx = ((size_t)b * L + l) * 512 + d0 + c * 4;
        float4 v = *(const float4*)(P + gidx);
        if (Q) {
            float4 qv = *(const float4*)(Q + gidx);
            v.x += qv.x; v.y += qv.y; v.z += qv.z; v.w += qv.w;
        } else if (Qb) {
            ushort4 qv = *(const ushort4*)(Qb + gidx);
            v.x += bf2f(qv.x); v.y += bf2f(qv.y);
            v.z += bf2f(qv.z); v.w += bf2f(qv.w);
        }
        *(float4*)(s + (size_t)i * 4) = v;
    }
    __syncthreads();
    // sliding-window MA + inline outputs: one column per thread, 4 segments
    {
        int d = threadIdx.x & 63, seg = threadIdx.x >> 6;
        int segLen = L >> 2;  // L = 96 or 144, both divisible by 4
        int l0 = seg * segLen;
        float S = 0.f;
#pragma unroll
        for (int j = -12; j <= 12; j++) S += s[iclamp(l0 + j, 0, L - 1) * 64 + d];
        for (int l = l0; l < l0 + segLen; l++) {
            float ma = S * (1.0f / 25.0f);
            float so = s[l * 64 + d] - ma;
            size_t idx = ((size_t)b * L + l) * 512 + d0 + d;
            SO[idx] = so;
            if (SOb) SOb[idx] = bfr(so);
            if (tmode == 1) TS[idx] = ma;
            else if (tmode == 2) TS[idx] += ma;
            S += s[iclamp(l + 13, 0, L - 1) * 64 + d]
               - s[iclamp(l - 12, 0, L - 1) * 64 + d];
        }
    }
}

// ---------------------------------------------------------------------------
__global__ __launch_bounds__(256) void ln_rows_kernel(const float* __restrict__ in,
                                                      const float* __restrict__ w,
                                                      const float* __restrict__ bvec,
                                                      float* __restrict__ out) {
    size_t row = blockIdx.x;
    const float* p = in + row * 512;
    int t = threadIdx.x;
    float v0 = p[t], v1 = p[t + 256];
    float s = v0 + v1, s2 = v0 * v0 + v1 * v1;
    for (int o = 32; o > 0; o >>= 1) {
        s += __shfl_xor(s, o, 64);
        s2 += __shfl_xor(s2, o, 64);
    }
    __shared__ float rs[4], rs2[4];
    int wid = t >> 6;
    if ((t & 63) == 0) { rs[wid] = s; rs2[wid] = s2; }
    __syncthreads();
    s = rs[0] + rs[1] + rs[2] + rs[3];
    s2 = rs2[0] + rs2[1] + rs2[2] + rs2[3];
    float mu = s * (1.0f / 512.0f);
    float var = s2 * (1.0f / 512.0f) - mu * mu;
    float r = rsqrtf(var + 1e-5f);
    out[row * 512 + t] = (v0 - mu) * r * w[t] + bvec[t];
    out[row * 512 + t + 256] = (v1 - mu) * r * w[t + 256] + bvec[t + 256];
}

// timesub (+ optional bf16 copy)
__global__ void timesub_kernel(float* __restrict__ X, unsigned short* __restrict__ Xb,
                               int L) {
    int b = blockIdx.x, d0 = blockIdx.y * 64;
    __shared__ float tile[144 * 64];
    __shared__ float mean[64];
    for (int i = threadIdx.x; i < L * 64; i += 256) {
        int l = i >> 6, d = i & 63;
        tile[i] = X[((size_t)b * L + l) * 512 + d0 + d];
    }
    __syncthreads();
    if (threadIdx.x < 64) {
        float sm = 0.f;
        for (int l = 0; l < L; l++) sm += tile[l * 64 + threadIdx.x];
        mean[threadIdx.x] = sm / (float)L;
    }
    __syncthreads();
    for (int i = threadIdx.x; i < L * 64; i += 256) {
        int l = i >> 6, d = i & 63;
        size_t idx = ((size_t)b * L + l) * 512 + d0 + d;
        float v = tile[i] - mean[d];
        X[idx] = v;
        if (Xb) Xb[idx] = bfr(v);
    }
}

// ---------------------------------------------------------------------------
__global__ __launch_bounds__(256) void final_v2(
    const float* __restrict__ XL, const float* __restrict__ TS,
    const float* __restrict__ TI, const float* __restrict__ trend_w,
    const float* __restrict__ proj_w, const float* __restrict__ proj_b,
    float* __restrict__ out) {
    int blk = blockIdx.x;
    int b = blk / 96, lo = blk - b * 96;
    int l = lo + 48;
    int lm = l - 1;
    int lp = (l == 143) ? 0 : l + 1;
    const float* ts = TS + (size_t)b * 144 * 512;
    const float* r0 = ts + (size_t)lm * 512;
    const float* r1 = ts + (size_t)l * 512;
    const float* r2 = ts + (size_t)lp * 512;
    const float* xl = XL + ((size_t)b * 144 + l) * 512;
    int t = threadIdx.x;
    float p[7];
#pragma unroll
    for (int c = 0; c < 7; c++) p[c] = 0.f;
#pragma unroll
    for (int dd = 0; dd < 2; dd++) {
        int d = t + dd * 256;
        float a0 = r0[d], a1 = r1[d], a2 = r2[d], x = xl[d];
#pragma unroll
        for (int c = 0; c < 7; c++) {
            const float* tw = trend_w + ((size_t)c * 512 + d) * 3;
            float v = a0 * tw[0] + a1 * tw[1] + a2 * tw[2];
            v = fmaf(x, proj_w[c * 512 + d], v);
            p[c] += v;
        }
    }
#pragma unroll
    for (int o = 32; o > 0; o >>= 1)
#pragma unroll
        for (int c = 0; c < 7; c++) p[c] += __shfl_xor(p[c], o, 64);
    __shared__ float red[4][7];
    int wid = t >> 6;
    if ((t & 63) == 0)
#pragma unroll
        for (int c = 0; c < 7; c++) red[wid][c] = p[c];
    __syncthreads();
    if (t < 7) {
        float v = red[0][t] + red[1][t] + red[2][t] + red[3][t]
                + TI[((size_t)b * 144 + l) * 7 + t] + proj_b[t];
        out[(size_t)blk * 7 + t] = v;
    }
}

// ---------------------------------------------------------------------------
static inline int cdiv(int a, int b) { return (a + b - 1) / b; }

extern "C" void kernel_launch(void* const* d_in, const int* in_sizes, int n_in,
                              void* d_out, int out_size, void* d_ws, size_t ws_size,
                              hipStream_t stream) {
    const float* x_enc      = (const float*)d_in[0];
    const float* x_mark_enc = (const float*)d_in[1];
    const float* x_mark_dec = (const float*)d_in[3];
    const float* enc_emb_conv_w = (const float*)d_in[4];
    const float* enc_emb_time_w = (const float*)d_in[5];
    const float* dec_emb_conv_w = (const float*)d_in[6];
    const float* dec_emb_time_w = (const float*)d_in[7];
    const float* enc_qw = (const float*)d_in[8];
    const float* enc_qb = (const float*)d_in[9];
    const float* enc_ow = (const float*)d_in[14];
    const float* enc_ob = (const float*)d_in[15];
    const float* enc_fw = (const float*)d_in[16];
    const float* enc_c1 = (const float*)d_in[17];
    const float* enc_c2 = (const float*)d_in[18];
    const float* enc_norm_w = (const float*)d_in[19];
    const float* enc_norm_b = (const float*)d_in[20];
    const float* ds_qw = (const float*)d_in[21];
    const float* ds_qb = (const float*)d_in[22];
    const float* ds_ow = (const float*)d_in[27];
    const float* ds_ob = (const float*)d_in[28];
    const float* ds_fw = (const float*)d_in[29];
    const float* dc_qw = (const float*)d_in[30];
    const float* dc_qb = (const float*)d_in[31];
    const float* dc_kw = (const float*)d_in[32];
    const float* dc_kb = (const float*)d_in[33];
    const float* dc_ow = (const float*)d_in[36];
    const float* dc_ob = (const float*)d_in[37];
    const float* dc_fw = (const float*)d_in[38];
    const float* dec_c1 = (const float*)d_in[39];
    const float* dec_c2 = (const float*)d_in[40];
    const float* dec_trend_w = (const float*)d_in[41];
    const float* dec_norm_w = (const float*)d_in[42];
    const float* dec_norm_b = (const float*)d_in[43];
    const float* proj_w = (const float*)d_in[44];
    const float* proj_b = (const float*)d_in[45];

    float* ws = (float*)d_ws;
    float* XD   = ws;
    float* TS   = ws + 9437184;
    float* XE   = ws + 18874368;
    unsigned short* XEb = (unsigned short*)(ws + 25165824);
    unsigned short* XDb = (unsigned short*)(ws + 28311552);
    float* SI   = ws + 33030144;
    float* TI   = ws + 33159168;
    float* TAB  = ws + 33288192;
    unsigned short* WF = (unsigned short*)(ws + 33320960);
    float* SC   = ws + 37646336;
    unsigned short* TdbE = (unsigned short*)(TAB);
    unsigned short* TdbD = (unsigned short*)(TAB + 6144);
    unsigned short* TibE = (unsigned short*)(TAB + 16384);
    unsigned short* TibD = (unsigned short*)(TAB + 20992);
    // embedding feature/weight buffers in tail slack (SC ends at 51277824)
    unsigned short* Fb  = (unsigned short*)(ws + 51277824);  // up to 18432*64 bf16
    unsigned short* Wcb = (unsigned short*)(ws + 51867648);  // 512*64 bf16

    unsigned short* enc_qw_b = WF;
    unsigned short* enc_ow_b = WF + 524288;
    unsigned short* enc_c1_b = WF + 1048576;
    unsigned short* enc_c2_b = WF + 3145728;
    unsigned short* ds_qw_b  = WF + 5242880;
    unsigned short* ds_ow_b  = WF + 5505024;
    unsigned short* dc_qw_b  = WF + 5767168;
    unsigned short* dc_kw_b  = WF + 6029312;
    unsigned short* dc_ow_b  = WF + 6291456;
    unsigned short* dec_c1_b = WF + 6553600;
    unsigned short* dec_c2_b = WF + 7602176;

    const size_t need_bytes = (size_t)53768192 * sizeof(float);
    if (ws_size < need_bytes) {
        zero_out_kernel<<<cdiv(out_size, 256), 256, 0, stream>>>((float*)d_out, out_size);
        return;
    }

    auto gemm = [&](const unsigned short* A, const unsigned short* W, const float* bias,
                    float* Cf, unsigned short* Cb, int rows, int N, int K,
                    int lda, int ldw, int gelu, int accum) {
        dim3 g(N / 128, rows / 128);
        gemm_bb<<<g, 256, 0, stream>>>(A, W, bias, Cf, Cb, N, K, lda, ldw, gelu, accum);
    };

    // ---- weight conversion (single fused dispatch)
    {
        F2BArgs fa;
        const float* srcs[11] = {enc_qw, enc_ow, enc_c1, enc_c2, ds_qw, ds_ow,
                                 dc_qw, dc_kw, dc_ow, dec_c1, dec_c2};
        unsigned short* dsts[11] = {enc_qw_b, enc_ow_b, enc_c1_b, enc_c2_b, ds_qw_b,
                                    ds_ow_b, dc_qw_b, dc_kw_b, dc_ow_b, dec_c1_b, dec_c2_b};
        const int ns[11] = {524288, 524288, 2097152, 2097152, 262144, 262144,
                            262144, 262144, 262144, 1048576, 1048576};
        int off = 0;
        fa.boff[0] = 0;
        for (int i = 0; i < 11; i++) {
            fa.s[i] = srcs[i];
            fa.d[i] = dsts[i];
            off += ns[i] / 1024;
            fa.boff[i + 1] = off;
        }
        f2b_multi<<<off, 256, 0, stream>>>(fa);
    }

    // ---- twiddle tables
    dtab_kernel<<<cdiv(128 * 96, 256), 256, 0, stream>>>(TdbE, 48, 96, 96);
    dtab_kernel<<<cdiv(128 * 160, 256), 256, 0, stream>>>(TdbD, 64, 144, 160);
    itab_kernel<<<cdiv(96 * 96, 256), 256, 0, stream>>>(TibE, 48, 96, 96);
    itab_kernel<<<cdiv(144 * 128, 256), 256, 0, stream>>>(TibD, 64, 144, 128);

    // ---- preprocess + encoder embed (as GEMM: F[12288][64] x Wc[512][64]^T)
    preprocess_kernel<<<cdiv(128 * 144 * 7, 256), 256, 0, stream>>>(x_enc, SI, TI);
    embed_wpack<<<2, 256, 0, stream>>>(enc_emb_conv_w, enc_emb_time_w, Wcb);
    embed_feat<<<48, 256, 0, stream>>>(x_enc, x_mark_enc, Fb, 96);
    gemm(Fb, Wcb, nullptr, XE, XEb, 12288, 512, 64, 64, 64, 0, 0);

    // ---- encoder layers (M=48)
    for (int l = 0; l < 2; l++) {
        const unsigned short* qwb = enc_qw_b + (size_t)l * 262144;
        const float* qb = enc_qb + (size_t)l * 512;
        const unsigned short* owb = enc_ow_b + (size_t)l * 262144;
        const float* ob = enc_ob + (size_t)l * 512;
        const float* fw = enc_fw + (size_t)l * 8 * 64 * 64 * 48 * 2;
        const unsigned short* c1b = enc_c1_b + (size_t)l * 1048576;
        const unsigned short* c2b = enc_c2_b + (size_t)l * 1048576;
        unsigned short* Pq = (unsigned short*)(SC);
        unsigned short* XT = (unsigned short*)(SC + 3145728);
        unsigned short* WB = (unsigned short*)(SC + 6291456);
        unsigned short* Yp = (unsigned short*)(SC + 9437184);
        unsigned short* Tidb = (unsigned short*)(SC);
        unsigned short* To_b = (unsigned short*)(SC + 3145728);  // bf16, over dead XT
        unsigned short* encYb = XDb;  // enc c2 bf16 scratch (XDb unused in encoder)

        gemm(XEb, qwb, qb, nullptr, Pq, 12288, 512, 512, 512, 512, 0, 0);
        dft_mfma2<<<dim3(1, 512), 256, 0, stream>>>(Pq, TdbE, XT, 96, 96, 48);
        wtrans3<<<dim3(16, 8), 256, 0, stream>>>(fw, WB, 48);
        mix_v2<<<dim3(48, 8), 256, 0, stream>>>(XT, WB, Yp, 48);
        idft_v2<<<dim3(1, 512), 256, 0, stream>>>(Yp, TibE, Tidb, 96, 96, 48, 1.f / 96.f);
        gemm(Tidb, owb, ob, nullptr, To_b, 12288, 512, 512, 512, 512, 0, 0);
        decomp_kernel<<<dim3(128, 8), 256, 0, stream>>>(
            XE, nullptr, To_b, XE, XEb, nullptr, 96, 0);
        unsigned short* hid = (unsigned short*)(SC);
        gemm(XEb, c1b, nullptr, nullptr, hid, 12288, 2048, 512, 512, 512, 1, 0);
        gemm(hid, c2b, nullptr, nullptr, encYb, 12288, 512, 2048, 2048, 2048, 0, 0);
        decomp_kernel<<<dim3(128, 8), 256, 0, stream>>>(
            XE, nullptr, encYb, XE, XEb, nullptr, 96, 0);
    }
    ln_rows_kernel<<<12288, 256, 0, stream>>>(XE, enc_norm_w, enc_norm_b, XE);
    timesub_kernel<<<dim3(128, 8), 256, 0, stream>>>(XE, XEb, 96);

    // ---- decoder embed (as GEMM)
    embed_wpack<<<2, 256, 0, stream>>>(dec_emb_conv_w, dec_emb_time_w, Wcb);
    embed_feat<<<72, 256, 0, stream>>>(SI, x_mark_dec, Fb, 144);
    gemm(Fb, Wcb, nullptr, XD, XDb, 18432, 512, 64, 64, 64, 0, 0);

    // ---- decoder self fourier block (M=64)
    {
        unsigned short* Pq = (unsigned short*)(SC);
        unsigned short* XT = (unsigned short*)(SC + 4718592);
        unsigned short* WB = (unsigned short*)(SC + 8912896);
        unsigned short* Yp = (unsigned short*)(SC);
        unsigned short* Tidb = (unsigned short*)(SC + 9437184);
        unsigned short* To_b = (unsigned short*)(SC);  // bf16, over dead Yp

        gemm(XDb, ds_qw_b, ds_qb, nullptr, Pq, 18432, 512, 512, 512, 512, 0, 0);
        dft_mfma2<<<dim3(1, 512), 256, 0, stream>>>(Pq, TdbD, XT, 144, 160, 64);
        wtrans3<<<dim3(16, 8), 256, 0, stream>>>(ds_fw, WB, 64);
        mix_v2<<<dim3(64, 8), 256, 0, stream>>>(XT, WB, Yp, 64);
        idft_v2<<<dim3(2, 512), 256, 0, stream>>>(Yp, TibD, Tidb, 144, 128, 64, 1.f / 144.f);
        gemm(Tidb, ds_ow_b, ds_ob, nullptr, To_b, 18432, 512, 512, 512, 512, 0, 0);
        decomp_kernel<<<dim3(128, 8), 256, 0, stream>>>(
            XD, nullptr, To_b, XD, XDb, TS, 144, 1);
    }

    // ---- cross attention
    {
        unsigned short* Pq  = (unsigned short*)(SC);
        unsigned short* XTQ = (unsigned short*)(SC + 4718592);
        unsigned short* Pk  = (unsigned short*)(SC);
        unsigned short* XTK = (unsigned short*)(SC + 8912896);
        unsigned* G         = (unsigned*)(SC);
        unsigned short* VT  = (unsigned short*)(SC + 3145728);
        unsigned short* WB  = (unsigned short*)(SC + 7340032);
        unsigned short* Yp  = (unsigned short*)(SC + 11534336);
        unsigned short* Tidb = (unsigned short*)(SC);
        unsigned short* To_b = (unsigned short*)(SC + 4718592);  // bf16, over dead XTQ/VT/WB

        gemm(XDb, dc_qw_b, dc_qb, nullptr, Pq, 18432, 512, 512, 512, 512, 0, 0);
        dft_mfma2<<<dim3(1, 512), 256, 0, stream>>>(Pq, TdbD, XTQ, 144, 160, 64);
        gemm(XEb, dc_kw_b, dc_kb, nullptr, Pk, 12288, 512, 512, 512, 512, 0, 0);
        dft_mfma2<<<dim3(1, 512), 256, 0, stream>>>(Pk, TdbE, XTK, 96, 96, 48);
        xqk3<<<dim3(128, 8), 256, 0, stream>>>(XTQ, XTK, G);
        xqkv3<<<dim3(128, 8), 256, 0, stream>>>(G, XTK, VT);
        wtrans3<<<dim3(16, 8), 256, 0, stream>>>(dc_fw, WB, 64);
        mix_v2<<<dim3(64, 8), 256, 0, stream>>>(VT, WB, Yp, 64);
        idft_v2<<<dim3(2, 512), 256, 0, stream>>>(Yp, TibD, Tidb, 144, 128, 64,
                                                  1.f / (144.f * 262144.f));
        gemm(Tidb, dc_ow_b, dc_ob, nullptr, To_b, 18432, 512, 512, 512, 512, 0, 0);
        decomp_kernel<<<dim3(128, 8), 256, 0, stream>>>(
            XD, nullptr, To_b, XD, XDb, TS, 144, 2);
    }

    // ---- decoder FFN: 2 chunks of N=1024; hid bf16 in SC, fout bf16 in XE area
    {
        unsigned short* hid = (unsigned short*)(SC);
        unsigned short* fout_b = (unsigned short*)XE;  // XE fp32 dead during dec FFN
        for (int j0 = 0; j0 < 2048; j0 += 1024) {
            gemm(XDb, dec_c1_b + (size_t)j0 * 512, nullptr, nullptr, hid,
                 18432, 1024, 512, 512, 512, 1, 0);
            gemm(hid, dec_c2_b + j0, nullptr, nullptr, fout_b,
                 18432, 512, 1024, 1024, 2048, 0, j0 > 0);
        }
        decomp_kernel<<<dim3(128, 8), 256, 0, stream>>>(
            XD, nullptr, fout_b, XD, nullptr, TS, 144, 2);
    }

    // ---- final norm + trend conv + projection
    ln_rows_kernel<<<18432, 256, 0, stream>>>(XD, dec_norm_w, dec_norm_b, XD);
    timesub_kernel<<<dim3(128, 8), 256, 0, stream>>>(XD, nullptr, 144);
    final_v2<<<12288, 256, 0, stream>>>(
        XD, TS, TI, dec_trend_w, proj_w, proj_b, (float*)d_out);
}

// Round 10
// 1286.289 us; speedup vs baseline: 1.0415x; 1.0415x over previous
//
#include <hip/hip_runtime.h>
#include <hip/hip_bf16.h>
#include <math.h>

// Model_45904610459674: FEDformer-style forecaster.
// Round 19: revert gemm_bb to R17 (R18's LDS epilogue regressed: fixed the
// write amplification but serialized the tail, 56->82us). New ONE lever
// (traffic class): the residual stream is bf16-only. The fp32 masters
// XE/XD (25/38MB) were read+written by every decomp/ln/timesub/final and
// double-written by embed gemms, yet all gemms already consume the bf16
// copies. Dropping them removes ~450 MB/iter. decomp reads bf16 P; embed
// gemms write Cb-only; ln_rows/timesub/final_v2 take bf16 I/O (stats fp32,
// in-place safe). TS (trend accum) stays fp32.
// R17 anchor: 1310 us, absmax 7.8e-3.
// Workspace: 53,768,192 floats = 215.07 MB (same guard).

#define PI_F 3.14159265358979323846f

typedef short bf16x8 __attribute__((ext_vector_type(8)));
typedef float f32x4 __attribute__((ext_vector_type(4)));

static __device__ __forceinline__ int iclamp(int v, int lo, int hi) {
    return v < lo ? lo : (v > hi ? hi : v);
}
static __device__ __forceinline__ unsigned pack2(float x, float y) {
    unsigned xu = __float_as_uint(x) + 0x8000u;
    unsigned yu = __float_as_uint(y) + 0x8000u;
    return (xu >> 16) | (yu & 0xFFFF0000u);
}
static __device__ __forceinline__ unsigned short bfr(float x) {
    return (unsigned short)((__float_as_uint(x) + 0x8000u) >> 16);
}
static __device__ __forceinline__ float bf2f(unsigned short s) {
    return __uint_as_float((unsigned)s << 16);
}

__global__ void zero_out_kernel(float* __restrict__ out, int n) {
    int i = blockIdx.x * 256 + threadIdx.x;
    if (i < n) out[i] = 0.f;
}

// fused fp32->bf16 for all 11 weight tensors in one dispatch.
struct F2BArgs {
    const float* s[11];
    unsigned short* d[11];
    int boff[12];
};
__global__ void f2b_multi(F2BArgs a) {
    int blk = blockIdx.x;
    int seg = 0;
    while (blk >= a.boff[seg + 1]) seg++;  // uniform scalar scan, <=11 iters
    int i = (blk - a.boff[seg]) * 1024 + threadIdx.x * 4;
    const float4 v = *(const float4*)(a.s[seg] + i);
    *(uint2*)(a.d[seg] + i) = make_uint2(pack2(v.x, v.y), pack2(v.z, v.w));
}

// ---------------------------------------------------------------------------
__global__ void preprocess_kernel(const float* __restrict__ xe,
                                  float* __restrict__ SI, float* __restrict__ TI) {
    int idx = blockIdx.x * 256 + threadIdx.x;
    if (idx >= 128 * 144 * 7) return;
    int c = idx % 7;
    int l = (idx / 7) % 144;
    int b = idx / (7 * 144);
    const float* xb = xe + (size_t)b * 96 * 7;
    if (l < 48) {
        int p = 48 + l;
        float sum = 0.f;
        for (int j = -12; j <= 12; j++) sum += xb[iclamp(p + j, 0, 95) * 7 + c];
        float ma = sum * (1.0f / 25.0f);
        SI[idx] = xb[p * 7 + c] - ma;
        TI[idx] = ma;
    } else {
        SI[idx] = 0.f;
        float m = 0.f;
        for (int l2 = 0; l2 < 96; l2++) m += xb[l2 * 7 + c];
        TI[idx] = m * (1.0f / 96.0f);
    }
}

// ---------------------------------------------------------------------------
// Embedding as GEMM: feature matrix F[row][k] bf16, K padded 25->64.
__global__ void embed_feat(const float* __restrict__ x, const float* __restrict__ mark,
                           unsigned short* __restrict__ F, int L) {
    int row = blockIdx.x * 256 + threadIdx.x;
    if (row >= 128 * L) return;
    int l = row % L;
    int b = row / L;
    int lm = (l == 0) ? L - 1 : l - 1;
    int lp = (l == L - 1) ? 0 : l + 1;
    const float* x0 = x + (size_t)b * L * 7;
    const float* mk = mark + (size_t)row * 4;
    union { unsigned short s[64]; uint4 u[8]; } f;
#pragma unroll
    for (int k = 0; k < 8; k++) f.u[k] = make_uint4(0u, 0u, 0u, 0u);
#pragma unroll
    for (int c = 0; c < 7; c++) {
        f.s[c * 3 + 0] = bfr(x0[lm * 7 + c]);
        f.s[c * 3 + 1] = bfr(x0[l * 7 + c]);
        f.s[c * 3 + 2] = bfr(x0[lp * 7 + c]);
    }
#pragma unroll
    for (int j = 0; j < 4; j++) f.s[21 + j] = bfr(mk[j]);
    uint4* dst = (uint4*)(F + (size_t)row * 64);
#pragma unroll
    for (int k = 0; k < 8; k++) dst[k] = f.u[k];
}

// packed embedding weight Wc[o][k] bf16, matching embed_feat's k layout
__global__ void embed_wpack(const float* __restrict__ cw, const float* __restrict__ tw,
                            unsigned short* __restrict__ Wc) {
    int o = blockIdx.x * 256 + threadIdx.x;
    if (o >= 512) return;
    union { unsigned short s[64]; uint4 u[8]; } f;
#pragma unroll
    for (int k = 0; k < 8; k++) f.u[k] = make_uint4(0u, 0u, 0u, 0u);
#pragma unroll
    for (int c = 0; c < 7; c++) {
        const float* w = cw + (o * 7 + c) * 3;
        f.s[c * 3 + 0] = bfr(w[0]);
        f.s[c * 3 + 1] = bfr(w[1]);
        f.s[c * 3 + 2] = bfr(w[2]);
    }
#pragma unroll
    for (int j = 0; j < 4; j++) f.s[21 + j] = bfr(tw[o * 4 + j]);
    uint4* dst = (uint4*)(Wc + (size_t)o * 64);
#pragma unroll
    for (int k = 0; k < 8; k++) dst[k] = f.u[k];
}

// ---------------------------------------------------------------------------
// gemm_bb: A,W bf16. Staging: global_load_lds 16B DMA, XOR-swizzled chunks.
// Epilogue (R17 form): Cf (fp32) and/or Cb (bf16); accum reads Cf if
// present, else Cb (bf16 accumulate — dec-FFN chunk sum).
__global__ __launch_bounds__(256, 4) void gemm_bb(
    const unsigned short* __restrict__ A, const unsigned short* __restrict__ W,
    const float* __restrict__ bias, float* __restrict__ Cf,
    unsigned short* __restrict__ Cb,
    int N, int K, int lda, int ldw, int gelu, int accum) {
    __shared__ unsigned short As[128 * 64];
    __shared__ unsigned short Ws[128 * 64];
    const int tid = threadIdx.x;
    const int lane = tid & 63, wv = tid >> 6;
    const int wm = (wv & 1) * 64, wn = (wv >> 1) * 64;
    const int q = lane >> 4, ln = lane & 15;
    const size_t bm = (size_t)blockIdx.y * 128;
    const size_t bn = (size_t)blockIdx.x * 128;

    f32x4 acc[4][4];
#pragma unroll
    for (int i = 0; i < 4; i++)
#pragma unroll
        for (int j = 0; j < 4; j++) acc[i][j] = (f32x4){0.f, 0.f, 0.f, 0.f};

    for (int k0 = 0; k0 < K; k0 += 64) {
#pragma unroll
        for (int t = 0; t < 4; t++) {
            int idx = (wv * 4 + t) * 64 + lane;
            int row = idx >> 3, cp = idx & 7;
            int cl = cp ^ (row & 7);
            __builtin_amdgcn_global_load_lds(
                (const __attribute__((address_space(1))) void*)(A + (bm + row) * lda + k0 + cl * 8),
                (__attribute__((address_space(3))) void*)(As + (size_t)(wv * 4 + t) * 512),
                16, 0, 0);
            __builtin_amdgcn_global_load_lds(
                (const __attribute__((address_space(1))) void*)(W + (bn + row) * ldw + k0 + cl * 8),
                (__attribute__((address_space(3))) void*)(Ws + (size_t)(wv * 4 + t) * 512),
                16, 0, 0);
        }
        __syncthreads();
#pragma unroll
        for (int kk = 0; kk < 64; kk += 32) {
            bf16x8 af[4], bfr4[4];
            const int cq = (kk >> 3) + q;
#pragma unroll
            for (int i = 0; i < 4; i++) {
                int r = wm + i * 16 + ln;
                af[i] = *(const bf16x8*)(As + r * 64 + ((cq ^ (r & 7)) * 8));
                int rw = wn + i * 16 + ln;
                bfr4[i] = *(const bf16x8*)(Ws + rw * 64 + ((cq ^ (rw & 7)) * 8));
            }
#pragma unroll
            for (int i = 0; i < 4; i++)
#pragma unroll
                for (int j = 0; j < 4; j++)
                    acc[i][j] = __builtin_amdgcn_mfma_f32_16x16x32_bf16(
                        af[i], bfr4[j], acc[i][j], 0, 0, 0);
        }
        __syncthreads();
    }
#pragma unroll
    for (int j = 0; j < 4; j++) {
        int col = (int)bn + wn + j * 16 + ln;
        float bv = bias ? bias[col] : 0.f;
#pragma unroll
        for (int i = 0; i < 4; i++) {
            size_t row0 = bm + wm + i * 16 + q * 4;
#pragma unroll
            for (int r = 0; r < 4; r++) {
                float v = acc[i][j][r] + bv;
                if (gelu) v = 0.5f * v * (1.f + erff(v * 0.70710678118654752f));
                size_t off = (row0 + r) * N + col;
                if (Cf) {
                    float* p = Cf + off;
                    if (accum) v += *p;
                    *p = v;
                } else if (accum) {
                    v += bf2f(Cb[off]);
                }
                if (Cb) Cb[off] = bfr(v);
            }
        }
    }
}

// ---------------------------------------------------------------------------
// twiddle tables (bf16)
__global__ void dtab_kernel(unsigned short* __restrict__ T, int M, int L, int ldk) {
    int i = blockIdx.x * 256 + threadIdx.x;
    if (i >= 128 * ldk) return;
    int n = i / ldk, k = i - n * ldk;
    float val = 0.f;
    if (n < 2 * M && k < L) {
        int m = n >> 1;
        int r = (m * k) % L;
        float ang = -2.f * PI_F * (float)r / (float)L;
        val = (n & 1) ? sinf(ang) : cosf(ang);
    }
    T[i] = bfr(val);
}
__global__ void itab_kernel(unsigned short* __restrict__ T, int M, int L, int K) {
    int i = blockIdx.x * 256 + threadIdx.x;
    if (i >= L * K) return;
    int n = i / K, k = i - n * K;
    int m = k >> 1;
    float c = (m == 0) ? 1.f : 2.f;
    int r = (m * n) % L;
    float ang = 2.f * PI_F * (float)r / (float)L;
    float val = (k & 1) ? -c * sinf(ang) : c * cosf(ang);
    T[i] = bfr(val);
}

// ---------------------------------------------------------------------------
// dft MFMA v2 (bf16 input): P bf16 [B*L,512] -> XT[h][m][b][2e+p] bf16
__global__ __launch_bounds__(256) void dft_mfma2(
    const unsigned short* __restrict__ P, const unsigned short* __restrict__ Tdb,
    unsigned short* __restrict__ XT, int L, int ldk, int M) {
    __shared__ unsigned short tile[128 * 130];
    const int tid = threadIdx.x;
    const int lane = tid & 63, wv = tid >> 6;
    const int wm = (wv & 1) * 64, wn = (wv >> 1) * 64;
    const int q = lane >> 4, ln = lane & 15;
    const int bm = blockIdx.y;
    const int b = bm >> 2, c0 = (bm & 3) * 128;
    const int h0 = c0 >> 6;
    const unsigned short* Pb = P + (size_t)b * L * 512;

    f32x4 acc[4][4];
#pragma unroll
    for (int i = 0; i < 4; i++)
#pragma unroll
        for (int j = 0; j < 4; j++) acc[i][j] = (f32x4){0.f, 0.f, 0.f, 0.f};

    for (int k0 = 0; k0 < L; k0 += 32) {
        bf16x8 af[4], bf[4];
        union FR { bf16x8 v; unsigned short s[8]; };
#pragma unroll
        for (int i = 0; i < 4; i++) {
            int c = c0 + wm + i * 16 + ln;
            FR fr;
#pragma unroll
            for (int t = 0; t < 8; t++) {
                int l = k0 + q * 8 + t;
                fr.s[t] = (l < L) ? Pb[(size_t)l * 512 + c] : (unsigned short)0;
            }
            af[i] = fr.v;
        }
#pragma unroll
        for (int j = 0; j < 4; j++) {
            int n = wn + j * 16 + ln;
            bf[j] = *(const bf16x8*)(Tdb + (size_t)n * ldk + k0 + q * 8);
        }
#pragma unroll
        for (int i = 0; i < 4; i++)
#pragma unroll
            for (int j = 0; j < 4; j++)
                acc[i][j] = __builtin_amdgcn_mfma_f32_16x16x32_bf16(
                    af[i], bf[j], acc[i][j], 0, 0, 0);
    }
#pragma unroll
    for (int j = 0; j < 4; j++) {
        int col = wn + j * 16 + ln;
#pragma unroll
        for (int i = 0; i < 4; i++) {
            int r0 = wm + i * 16 + q * 4;
#pragma unroll
            for (int r = 0; r < 4; r++)
                tile[(r0 + r) * 130 + col] = bfr(acc[i][j][r]);
        }
    }
    __syncthreads();
    unsigned* XTu = (unsigned*)XT;
    for (int idx = tid; idx < 2 * M * 64; idx += 256) {
        int chunk = idx >> 6, e = idx & 63;
        int h2 = chunk / M, m = chunk - h2 * M;
        unsigned v = *(const unsigned*)&tile[(h2 * 64 + e) * 130 + 2 * m];
        XTu[((size_t)((h0 + h2) * M + m) * 128 + b) * 64 + e] = v;
    }
}

// ---------------------------------------------------------------------------
// wtrans3: w[h][e][o][m][2] fp32 -> WB[(h*M+m)][n=2o+q][k=2e+p] bf16
__global__ __launch_bounds__(256) void wtrans3(
    const float* __restrict__ w, unsigned short* __restrict__ WB, int M) {
    __shared__ float Lre[16 * 289], Lim[16 * 289];
    const int h = blockIdx.y;
    const int ot = blockIdx.x >> 1, et = blockIdx.x & 1;
    const int o0 = ot * 8, e0 = et * 32;
    const int tid = threadIdx.x;
    unsigned* WBu = (unsigned*)WB;
    for (int mc = 0; mc < M; mc += 16) {
        for (int idx = tid; idx < 4096; idx += 256) {
            int e = idx >> 7, o = (idx >> 4) & 7, mm = idx & 15;
            const float2 v = *(const float2*)(
                w + ((((size_t)h * 64 + e0 + e) * 64 + o0 + o) * M + mc + mm) * 2);
            Lre[mm * 289 + e * 9 + o] = v.x;
            Lim[mm * 289 + e * 9 + o] = v.y;
        }
        __syncthreads();
        for (int widx = tid; widx < 8192; widx += 256) {
            int mm = widx >> 9, no = (widx >> 5) & 15, e = widx & 31;
            int ol = no >> 1, qn = no & 1;
            float re = Lre[mm * 289 + e * 9 + ol];
            float im = Lim[mm * 289 + e * 9 + ol];
            unsigned v = qn ? pack2(im, re) : pack2(re, -im);
            WBu[((size_t)(h * M + mc + mm) * 128 + 2 * (o0 + ol) + qn) * 64 + e0 + e] = v;
        }
        __syncthreads();
    }
}

// ---------------------------------------------------------------------------
// mix_v2: per (h,m): Y'[b][n] = sum_k XT[hm][b][k]*WB[hm][n][k], b128 loads
__global__ __launch_bounds__(256) void mix_v2(
    const unsigned short* __restrict__ XT, const unsigned short* __restrict__ WB,
    unsigned short* __restrict__ Yp, int M) {
    __shared__ unsigned short tile[128 * 130];
    const int m = blockIdx.x, h = blockIdx.y;
    const int tid = threadIdx.x;
    const int lane = tid & 63, wv = tid >> 6;
    const int wm = (wv & 1) * 64, wn = (wv >> 1) * 64;
    const int q = lane >> 4, ln = lane & 15;
    const size_t hm = (size_t)h * M + m;
    const unsigned short* Ab = XT + hm * 16384;
    const unsigned short* Bb = WB + hm * 16384;

    f32x4 acc[4][4];
#pragma unroll
    for (int i = 0; i < 4; i++)
#pragma unroll
        for (int j = 0; j < 4; j++) acc[i][j] = (f32x4){0.f, 0.f, 0.f, 0.f};

#pragma unroll
    for (int k0 = 0; k0 < 128; k0 += 32) {
        bf16x8 af[4], bf[4];
#pragma unroll
        for (int i = 0; i < 4; i++)
            af[i] = *(const bf16x8*)(Ab + (size_t)(wm + i * 16 + ln) * 128 + k0 + q * 8);
#pragma unroll
        for (int j = 0; j < 4; j++)
            bf[j] = *(const bf16x8*)(Bb + (size_t)(wn + j * 16 + ln) * 128 + k0 + q * 8);
#pragma unroll
        for (int i = 0; i < 4; i++)
#pragma unroll
            for (int j = 0; j < 4; j++)
                acc[i][j] = __builtin_amdgcn_mfma_f32_16x16x32_bf16(
                    af[i], bf[j], acc[i][j], 0, 0, 0);
    }
#pragma unroll
    for (int j = 0; j < 4; j++) {
        int col = wn + j * 16 + ln;
#pragma unroll
        for (int i = 0; i < 4; i++) {
            int r0 = wm + i * 16 + q * 4;
#pragma unroll
            for (int r = 0; r < 4; r++)
                tile[(r0 + r) * 130 + col] = bfr(acc[i][j][r]);
        }
    }
    __syncthreads();
    unsigned* Yu = (unsigned*)Yp;
    for (int idx = tid; idx < 128 * 64; idx += 256) {
        int b = idx >> 6, dw = idx & 63;
        unsigned v = *(const unsigned*)&tile[b * 130 + 2 * dw];
        Yu[(hm * 128 + b) * 64 + dw] = v;
    }
}

// ---------------------------------------------------------------------------
// idft_v2: Out bf16 [(b,h,o)*L + l] = bf16(s * sum_k Y'[..][k]*Ti[l][k])
__global__ __launch_bounds__(256) void idft_v2(
    const unsigned short* __restrict__ Yp, const unsigned short* __restrict__ Tib,
    unsigned short* __restrict__ Out, int L, int K, int M, float s) {
    __shared__ unsigned short sh[2 * 64 * 132];
    const int tid = threadIdx.x;
    const int lane = tid & 63, wv = tid >> 6;
    const int wm = (wv & 1) * 64, wn = (wv >> 1) * 64;
    const int q = lane >> 4, ln = lane & 15;
    const int bm = blockIdx.y;
    const int b = bm >> 2, h0 = (bm & 3) * 2;
    const int bn = blockIdx.x * 128;

    const unsigned* Yu = (const unsigned*)Yp;
    for (int idx = tid; idx < 2 * M * 64; idx += 256) {
        int chunk = idx >> 6, dw = idx & 63;
        int h2 = chunk / M, m = chunk - h2 * M;
        unsigned v = Yu[((size_t)((h0 + h2) * M + m) * 128 + b) * 64 + dw];
        *(unsigned*)&sh[chunk * 132 + 2 * dw] = v;
    }
    __syncthreads();

    f32x4 acc[4][4];
#pragma unroll
    for (int i = 0; i < 4; i++)
#pragma unroll
        for (int j = 0; j < 4; j++) acc[i][j] = (f32x4){0.f, 0.f, 0.f, 0.f};

    for (int k0 = 0; k0 < K; k0 += 32) {
        bf16x8 af[4], bf[4];
        union FR { bf16x8 v; unsigned u[4]; };
#pragma unroll
        for (int i = 0; i < 4; i++) {
            int lr = wm + i * 16 + ln;
            int h2 = lr >> 6, o = lr & 63;
            FR fr;
#pragma unroll
            for (int jj = 0; jj < 4; jj++) {
                int m = (k0 >> 1) + q * 4 + jj;
                fr.u[jj] = *(const unsigned*)&sh[(h2 * M + m) * 132 + 2 * o];
            }
            af[i] = fr.v;
        }
#pragma unroll
        for (int j = 0; j < 4; j++) {
            int n = bn + wn + j * 16 + ln;
            if (n < L) bf[j] = *(const bf16x8*)(Tib + (size_t)n * K + k0 + q * 8);
            else bf[j] = (bf16x8){0, 0, 0, 0, 0, 0, 0, 0};
        }
#pragma unroll
        for (int i = 0; i < 4; i++)
#pragma unroll
            for (int j = 0; j < 4; j++)
                acc[i][j] = __builtin_amdgcn_mfma_f32_16x16x32_bf16(
                    af[i], bf[j], acc[i][j], 0, 0, 0);
    }
#pragma unroll
    for (int j = 0; j < 4; j++) {
        int col = bn + wn + j * 16 + ln;
        if (col >= L) continue;
#pragma unroll
        for (int i = 0; i < 4; i++) {
            int row0 = bm * 128 + wm + i * 16 + q * 4;
#pragma unroll
            for (int r = 0; r < 4; r++)
                Out[(size_t)(row0 + r) * L + col] = bfr(acc[i][j][r] * s);
        }
    }
}

// ---------------------------------------------------------------------------
// xqk3: per (b,h): S = Q^T [Kre|Kim] via 64x96x128 bf16 MFMA, tanh -> G.
__global__ __launch_bounds__(256) void xqk3(
    const unsigned short* __restrict__ XTQ, const unsigned short* __restrict__ XTK,
    unsigned* __restrict__ G) {
    __shared__ __align__(16) unsigned char sm[43520];
    unsigned short* Qs = (unsigned short*)sm;            // [64][136]
    unsigned short* Bs = (unsigned short*)(sm + 17408);  // [96][136]
    float* Ss = (float*)sm;                              // [64][100] alias
    const int b = blockIdx.x, h = blockIdx.y;
    const int tid = threadIdx.x;
    const int lane = tid & 63, wv = tid >> 6;
    const int wm = (wv & 1) * 32, wn = (wv >> 1) * 48;
    const int q = lane >> 4, ln = lane & 15;

    const uint4* Qg = (const uint4*)XTQ;
    for (int i = tid; i < 64 * 16; i += 256) {
        int x = i >> 4, c = i & 15;
        *(uint4*)(Qs + x * 136 + c * 8) = Qg[((size_t)(h * 64 + x) * 128 + b) * 16 + c];
    }
    const unsigned* Ku = (const unsigned*)XTK;
    unsigned* Bu = (unsigned*)Bs;
    for (int i = tid; i < 48 * 64; i += 256) {
        int y = i >> 6, e = i & 63;
        unsigned v = Ku[((size_t)(h * 48 + y) * 128 + b) * 64 + e];
        Bu[y * 68 + e] = v ^ 0x80000000u;
        Bu[(48 + y) * 68 + e] = (v >> 16) | (v << 16);
    }
    __syncthreads();

    f32x4 acc[2][3];
#pragma unroll
    for (int i = 0; i < 2; i++)
#pragma unroll
        for (int j = 0; j < 3; j++) acc[i][j] = (f32x4){0.f, 0.f, 0.f, 0.f};

#pragma unroll
    for (int k0 = 0; k0 < 128; k0 += 32) {
        bf16x8 af[2], bf[3];
#pragma unroll
        for (int i = 0; i < 2; i++)
            af[i] = *(const bf16x8*)(Qs + (wm + i * 16 + ln) * 136 + k0 + q * 8);
#pragma unroll
        for (int j = 0; j < 3; j++)
            bf[j] = *(const bf16x8*)(Bs + (wn + j * 16 + ln) * 136 + k0 + q * 8);
#pragma unroll
        for (int i = 0; i < 2; i++)
#pragma unroll
            for (int j = 0; j < 3; j++)
                acc[i][j] = __builtin_amdgcn_mfma_f32_16x16x32_bf16(
                    af[i], bf[j], acc[i][j], 0, 0, 0);
    }
    __syncthreads();   // safe to alias Ss over Qs/Bs
#pragma unroll
    for (int j = 0; j < 3; j++) {
        int col = wn + j * 16 + ln;
#pragma unroll
        for (int i = 0; i < 2; i++) {
            int r0 = wm + i * 16 + q * 4;
#pragma unroll
            for (int r = 0; r < 4; r++)
                Ss[(r0 + r) * 100 + col] = acc[i][j][r];
        }
    }
    __syncthreads();
    for (int i = tid; i < 3072; i += 256) {
        int x = i / 48, y = i - x * 48;
        float re = Ss[x * 100 + y], im = Ss[x * 100 + 48 + y];
        float a2 = 2.f * re, b2 = 2.f * im;
        a2 = fminf(fmaxf(a2, -80.f), 80.f);
        float denom = coshf(a2) + cosf(b2);
        G[((size_t)(b * 8 + h) * 64 + x) * 48 + y] =
            pack2(sinhf(a2) / denom, sinf(b2) / denom);
    }
}

// ---------------------------------------------------------------------------
// xqkv3: per (b,h): V = G · B2 via 64x128x96 bf16 MFMA.
__global__ __launch_bounds__(256) void xqkv3(
    const unsigned* __restrict__ G, const unsigned short* __restrict__ XTK,
    unsigned short* __restrict__ VT) {
    __shared__ __align__(16) unsigned char sm[26624];
    unsigned short* Bs = (unsigned short*)sm;   // [128][104]
    unsigned short* Vs = (unsigned short*)sm;   // [64][132] alias after MFMA
    const int b = blockIdx.x, h = blockIdx.y;
    const int tid = threadIdx.x;
    const int lane = tid & 63, wv = tid >> 6;
    const int wm = (wv & 1) * 32, wn = (wv >> 1) * 64;
    const int q = lane >> 4, ln = lane & 15;

    const unsigned* Ku = (const unsigned*)XTK;
    unsigned* Bu = (unsigned*)Bs;
    for (int i = tid; i < 48 * 64; i += 256) {
        int y = i >> 6, e = i & 63;
        unsigned v = Ku[((size_t)(h * 48 + y) * 128 + b) * 64 + e];
        Bu[(2 * e) * 52 + y] = v ^ 0x80000000u;          // (kr,-ki)
        Bu[(2 * e + 1) * 52 + y] = (v >> 16) | (v << 16); // (ki,kr)
    }
    __syncthreads();

    const unsigned short* Ag = (const unsigned short*)G + (size_t)(b * 8 + h) * 6144;
    f32x4 acc[2][4];
#pragma unroll
    for (int i = 0; i < 2; i++)
#pragma unroll
        for (int j = 0; j < 4; j++) acc[i][j] = (f32x4){0.f, 0.f, 0.f, 0.f};

#pragma unroll
    for (int k0 = 0; k0 < 96; k0 += 32) {
        bf16x8 af[2], bf[4];
#pragma unroll
        for (int i = 0; i < 2; i++)
            af[i] = *(const bf16x8*)(Ag + (wm + i * 16 + ln) * 96 + k0 + q * 8);
#pragma unroll
        for (int j = 0; j < 4; j++)
            bf[j] = *(const bf16x8*)(Bs + (wn + j * 16 + ln) * 104 + k0 + q * 8);
#pragma unroll
        for (int i = 0; i < 2; i++)
#pragma unroll
            for (int j = 0; j < 4; j++)
                acc[i][j] = __builtin_amdgcn_mfma_f32_16x16x32_bf16(
                    af[i], bf[j], acc[i][j], 0, 0, 0);
    }
    __syncthreads();   // alias Vs over Bs
#pragma unroll
    for (int j = 0; j < 4; j++) {
        int col = wn + j * 16 + ln;
#pragma unroll
        for (int i = 0; i < 2; i++) {
            int r0 = wm + i * 16 + q * 4;
#pragma unroll
            for (int r = 0; r < 4; r++)
                Vs[(r0 + r) * 132 + col] = bfr(acc[i][j][r]);
        }
    }
    __syncthreads();
    unsigned* Vu = (unsigned*)VT;
    for (int i = tid; i < 64 * 64; i += 256) {
        int x = i >> 6, dw = i & 63;
        Vu[((size_t)(h * 64 + x) * 128 + b) * 64 + dw] = *(unsigned*)&Vs[x * 132 + 2 * dw];
    }
}

// ---------------------------------------------------------------------------
// series_decomp v4: bf16-only residual stream. Pb/Qb bf16 in, SOb bf16 out
// (in-place on Pb is safe: all global reads happen in phase 1, each block
// owns its (b, d-chunk) rows exclusively). TS stays fp32. Sliding-window
// MA with inline coalesced writes (summation order == R16/R17).
__global__ void decomp_kernel(const unsigned short* __restrict__ Pb,
                              const unsigned short* __restrict__ Qb,
                              unsigned short* __restrict__ SOb,
                              float* __restrict__ TS, int L, int tmode) {
    int b = blockIdx.x, d0 = blockIdx.y * 64;
    __shared__ float s[144 * 64];
    const int nvec = L * 16;  // 4-elem chunks per row of 64
    for (int i = threadIdx.x; i < nvec; i += 256) {
        int l = i >> 4, c = i & 15;
        size_t gidx = ((size_t)b * L + l) * 512 + d0 + c * 4;
        ushort4 pv = *(const ushort4*)(Pb + gidx);
        float4 v = make_float4(bf2f(pv.x), bf2f(pv.y), bf2f(pv.z), bf2f(pv.w));
        if (Qb) {
            ushort4 qv = *(const ushort4*)(Qb + gidx);
            v.x += bf2f(qv.x); v.y += bf2f(qv.y);
            v.z += bf2f(qv.z); v.w += bf2f(qv.w);
        }
        *(float4*)(s + (size_t)i * 4) = v;
    }
    __syncthreads();
    {
        int d = threadIdx.x & 63, seg = threadIdx.x >> 6;
        int segLen = L >> 2;  // L = 96 or 144, both divisible by 4
        int l0 = seg * segLen;
        float S = 0.f;
#pragma unroll
        for (int j = -12; j <= 12; j++) S += s[iclamp(l0 + j, 0, L - 1) * 64 + d];
        for (int l = l0; l < l0 + segLen; l++) {
            float ma = S * (1.0f / 25.0f);
            float so = s[l * 64 + d] - ma;
            size_t idx = ((size_t)b * L + l) * 512 + d0 + d;
            SOb[idx] = bfr(so);
            if (tmode == 1) TS[idx] = ma;
            else if (tmode == 2) TS[idx] += ma;
            S += s[iclamp(l + 13, 0, L - 1) * 64 + d]
               - s[iclamp(l - 12, 0, L - 1) * 64 + d];
        }
    }
}

// ---------------------------------------------------------------------------
// ln_rows bf16 in/out (in-place safe: each thread writes only its own 2
// elements, after the block reduction).
__global__ __launch_bounds__(256) void ln_rows_kernel(
    const unsigned short* __restrict__ in, const float* __restrict__ w,
    const float* __restrict__ bvec, unsigned short* __restrict__ out) {
    size_t row = blockIdx.x;
    const unsigned short* p = in + row * 512;
    int t = threadIdx.x;
    float v0 = bf2f(p[t]), v1 = bf2f(p[t + 256]);
    float s = v0 + v1, s2 = v0 * v0 + v1 * v1;
    for (int o = 32; o > 0; o >>= 1) {
        s += __shfl_xor(s, o, 64);
        s2 += __shfl_xor(s2, o, 64);
    }
    __shared__ float rs[4], rs2[4];
    int wid = t >> 6;
    if ((t & 63) == 0) { rs[wid] = s; rs2[wid] = s2; }
    __syncthreads();
    s = rs[0] + rs[1] + rs[2] + rs[3];
    s2 = rs2[0] + rs2[1] + rs2[2] + rs2[3];
    float mu = s * (1.0f / 512.0f);
    float var = s2 * (1.0f / 512.0f) - mu * mu;
    float r = rsqrtf(var + 1e-5f);
    out[row * 512 + t] = bfr((v0 - mu) * r * w[t] + bvec[t]);
    out[row * 512 + t + 256] = bfr((v1 - mu) * r * w[t + 256] + bvec[t + 256]);
}

// timesub bf16 in-place
__global__ void timesub_kernel(unsigned short* __restrict__ X, int L) {
    int b = blockIdx.x, d0 = blockIdx.y * 64;
    __shared__ float tile[144 * 64];
    __shared__ float mean[64];
    for (int i = threadIdx.x; i < L * 64; i += 256) {
        int l = i >> 6, d = i & 63;
        tile[i] = bf2f(X[((size_t)b * L + l) * 512 + d0 + d]);
    }
    __syncthreads();
    if (threadIdx.x < 64) {
        float sm = 0.f;
        for (int l = 0; l < L; l++) sm += tile[l * 64 + threadIdx.x];
        mean[threadIdx.x] = sm / (float)L;
    }
    __syncthreads();
    for (int i = threadIdx.x; i < L * 64; i += 256) {
        int l = i >> 6, d = i & 63;
        X[((size_t)b * L + l) * 512 + d0 + d] = bfr(tile[i] - mean[d]);
    }
}

// ---------------------------------------------------------------------------
__global__ __launch_bounds__(256) void final_v2(
    const unsigned short* __restrict__ XLb, const float* __restrict__ TS,
    const float* __restrict__ TI, const float* __restrict__ trend_w,
    const float* __restrict__ proj_w, const float* __restrict__ proj_b,
    float* __restrict__ out) {
    int blk = blockIdx.x;
    int b = blk / 96, lo = blk - b * 96;
    int l = lo + 48;
    int lm = l - 1;
    int lp = (l == 143) ? 0 : l + 1;
    const float* ts = TS + (size_t)b * 144 * 512;
    const float* r0 = ts + (size_t)lm * 512;
    const float* r1 = ts + (size_t)l * 512;
    const float* r2 = ts + (size_t)lp * 512;
    const unsigned short* xl = XLb + ((size_t)b * 144 + l) * 512;
    int t = threadIdx.x;
    float p[7];
#pragma unroll
    for (int c = 0; c < 7; c++) p[c] = 0.f;
#pragma unroll
    for (int dd = 0; dd < 2; dd++) {
        int d = t + dd * 256;
        float a0 = r0[d], a1 = r1[d], a2 = r2[d], x = bf2f(xl[d]);
#pragma unroll
        for (int c = 0; c < 7; c++) {
            const float* tw = trend_w + ((size_t)c * 512 + d) * 3;
            float v = a0 * tw[0] + a1 * tw[1] + a2 * tw[2];
            v = fmaf(x, proj_w[c * 512 + d], v);
            p[c] += v;
        }
    }
#pragma unroll
    for (int o = 32; o > 0; o >>= 1)
#pragma unroll
        for (int c = 0; c < 7; c++) p[c] += __shfl_xor(p[c], o, 64);
    __shared__ float red[4][7];
    int wid = t >> 6;
    if ((t & 63) == 0)
#pragma unroll
        for (int c = 0; c < 7; c++) red[wid][c] = p[c];
    __syncthreads();
    if (t < 7) {
        float v = red[0][t] + red[1][t] + red[2][t] + red[3][t]
                + TI[((size_t)b * 144 + l) * 7 + t] + proj_b[t];
        out[(size_t)blk * 7 + t] = v;
    }
}

// ---------------------------------------------------------------------------
static inline int cdiv(int a, int b) { return (a + b - 1) / b; }

extern "C" void kernel_launch(void* const* d_in, const int* in_sizes, int n_in,
                              void* d_out, int out_size, void* d_ws, size_t ws_size,
                              hipStream_t stream) {
    const float* x_enc      = (const float*)d_in[0];
    const float* x_mark_enc = (const float*)d_in[1];
    const float* x_mark_dec = (const float*)d_in[3];
    const float* enc_emb_conv_w = (const float*)d_in[4];
    const float* enc_emb_time_w = (const float*)d_in[5];
    const float* dec_emb_conv_w = (const float*)d_in[6];
    const float* dec_emb_time_w = (const float*)d_in[7];
    const float* enc_qw = (const float*)d_in[8];
    const float* enc_qb = (const float*)d_in[9];
    const float* enc_ow = (const float*)d_in[14];
    const float* enc_ob = (const float*)d_in[15];
    const float* enc_fw = (const float*)d_in[16];
    const float* enc_c1 = (const float*)d_in[17];
    const float* enc_c2 = (const float*)d_in[18];
    const float* enc_norm_w = (const float*)d_in[19];
    const float* enc_norm_b = (const float*)d_in[20];
    const float* ds_qw = (const float*)d_in[21];
    const float* ds_qb = (const float*)d_in[22];
    const float* ds_ow = (const float*)d_in[27];
    const float* ds_ob = (const float*)d_in[28];
    const float* ds_fw = (const float*)d_in[29];
    const float* dc_qw = (const float*)d_in[30];
    const float* dc_qb = (const float*)d_in[31];
    const float* dc_kw = (const float*)d_in[32];
    const float* dc_kb = (const float*)d_in[33];
    const float* dc_ow = (const float*)d_in[36];
    const float* dc_ob = (const float*)d_in[37];
    const float* dc_fw = (const float*)d_in[38];
    const float* dec_c1 = (const float*)d_in[39];
    const float* dec_c2 = (const float*)d_in[40];
    const float* dec_trend_w = (const float*)d_in[41];
    const float* dec_norm_w = (const float*)d_in[42];
    const float* dec_norm_b = (const float*)d_in[43];
    const float* proj_w = (const float*)d_in[44];
    const float* proj_b = (const float*)d_in[45];

    float* ws = (float*)d_ws;
    float* XD   = ws;            // fp32 area now scratch only
    float* TS   = ws + 9437184;
    float* XE   = ws + 18874368; // fp32 area now scratch only
    unsigned short* XEb = (unsigned short*)(ws + 25165824);
    unsigned short* XDb = (unsigned short*)(ws + 28311552);
    float* SI   = ws + 33030144;
    float* TI   = ws + 33159168;
    float* TAB  = ws + 33288192;
    unsigned short* WF = (unsigned short*)(ws + 33320960);
    float* SC   = ws + 37646336;
    unsigned short* TdbE = (unsigned short*)(TAB);
    unsigned short* TdbD = (unsigned short*)(TAB + 6144);
    unsigned short* TibE = (unsigned short*)(TAB + 16384);
    unsigned short* TibD = (unsigned short*)(TAB + 20992);
    unsigned short* Fb  = (unsigned short*)(ws + 51277824);  // up to 18432*64 bf16
    unsigned short* Wcb = (unsigned short*)(ws + 51867648);  // 512*64 bf16

    unsigned short* enc_qw_b = WF;
    unsigned short* enc_ow_b = WF + 524288;
    unsigned short* enc_c1_b = WF + 1048576;
    unsigned short* enc_c2_b = WF + 3145728;
    unsigned short* ds_qw_b  = WF + 5242880;
    unsigned short* ds_ow_b  = WF + 5505024;
    unsigned short* dc_qw_b  = WF + 5767168;
    unsigned short* dc_kw_b  = WF + 6029312;
    unsigned short* dc_ow_b  = WF + 6291456;
    unsigned short* dec_c1_b = WF + 6553600;
    unsigned short* dec_c2_b = WF + 7602176;

    const size_t need_bytes = (size_t)53768192 * sizeof(float);
    if (ws_size < need_bytes) {
        zero_out_kernel<<<cdiv(out_size, 256), 256, 0, stream>>>((float*)d_out, out_size);
        return;
    }

    auto gemm = [&](const unsigned short* A, const unsigned short* W, const float* bias,
                    float* Cf, unsigned short* Cb, int rows, int N, int K,
                    int lda, int ldw, int gelu, int accum) {
        dim3 g(N / 128, rows / 128);
        gemm_bb<<<g, 256, 0, stream>>>(A, W, bias, Cf, Cb, N, K, lda, ldw, gelu, accum);
    };

    // ---- weight conversion (single fused dispatch)
    {
        F2BArgs fa;
        const float* srcs[11] = {enc_qw, enc_ow, enc_c1, enc_c2, ds_qw, ds_ow,
                                 dc_qw, dc_kw, dc_ow, dec_c1, dec_c2};
        unsigned short* dsts[11] = {enc_qw_b, enc_ow_b, enc_c1_b, enc_c2_b, ds_qw_b,
                                    ds_ow_b, dc_qw_b, dc_kw_b, dc_ow_b, dec_c1_b, dec_c2_b};
        const int ns[11] = {524288, 524288, 2097152, 2097152, 262144, 262144,
                            262144, 262144, 262144, 1048576, 1048576};
        int off = 0;
        fa.boff[0] = 0;
        for (int i = 0; i < 11; i++) {
            fa.s[i] = srcs[i];
            fa.d[i] = dsts[i];
            off += ns[i] / 1024;
            fa.boff[i + 1] = off;
        }
        f2b_multi<<<off, 256, 0, stream>>>(fa);
    }

    // ---- twiddle tables
    dtab_kernel<<<cdiv(128 * 96, 256), 256, 0, stream>>>(TdbE, 48, 96, 96);
    dtab_kernel<<<cdiv(128 * 160, 256), 256, 0, stream>>>(TdbD, 64, 144, 160);
    itab_kernel<<<cdiv(96 * 96, 256), 256, 0, stream>>>(TibE, 48, 96, 96);
    itab_kernel<<<cdiv(144 * 128, 256), 256, 0, stream>>>(TibD, 64, 144, 128);

    // ---- preprocess + encoder embed (as GEMM; bf16-only output)
    preprocess_kernel<<<cdiv(128 * 144 * 7, 256), 256, 0, stream>>>(x_enc, SI, TI);
    embed_wpack<<<2, 256, 0, stream>>>(enc_emb_conv_w, enc_emb_time_w, Wcb);
    embed_feat<<<48, 256, 0, stream>>>(x_enc, x_mark_enc, Fb, 96);
    gemm(Fb, Wcb, nullptr, nullptr, XEb, 12288, 512, 64, 64, 64, 0, 0);

    // ---- encoder layers (M=48)
    for (int l = 0; l < 2; l++) {
        const unsigned short* qwb = enc_qw_b + (size_t)l * 262144;
        const float* qb = enc_qb + (size_t)l * 512;
        const unsigned short* owb = enc_ow_b + (size_t)l * 262144;
        const float* ob = enc_ob + (size_t)l * 512;
        const float* fw = enc_fw + (size_t)l * 8 * 64 * 64 * 48 * 2;
        const unsigned short* c1b = enc_c1_b + (size_t)l * 1048576;
        const unsigned short* c2b = enc_c2_b + (size_t)l * 1048576;
        unsigned short* Pq = (unsigned short*)(SC);
        unsigned short* XT = (unsigned short*)(SC + 3145728);
        unsigned short* WB = (unsigned short*)(SC + 6291456);
        unsigned short* Yp = (unsigned short*)(SC + 9437184);
        unsigned short* Tidb = (unsigned short*)(SC);
        unsigned short* To_b = (unsigned short*)(SC + 3145728);  // bf16, over dead XT
        unsigned short* encYb = XDb;  // enc c2 bf16 scratch (XDb unused in encoder)

        gemm(XEb, qwb, qb, nullptr, Pq, 12288, 512, 512, 512, 512, 0, 0);
        dft_mfma2<<<dim3(1, 512), 256, 0, stream>>>(Pq, TdbE, XT, 96, 96, 48);
        wtrans3<<<dim3(16, 8), 256, 0, stream>>>(fw, WB, 48);
        mix_v2<<<dim3(48, 8), 256, 0, stream>>>(XT, WB, Yp, 48);
        idft_v2<<<dim3(1, 512), 256, 0, stream>>>(Yp, TibE, Tidb, 96, 96, 48, 1.f / 96.f);
        gemm(Tidb, owb, ob, nullptr, To_b, 12288, 512, 512, 512, 512, 0, 0);
        decomp_kernel<<<dim3(128, 8), 256, 0, stream>>>(
            XEb, To_b, XEb, nullptr, 96, 0);
        unsigned short* hid = (unsigned short*)(SC);
        gemm(XEb, c1b, nullptr, nullptr, hid, 12288, 2048, 512, 512, 512, 1, 0);
        gemm(hid, c2b, nullptr, nullptr, encYb, 12288, 512, 2048, 2048, 2048, 0, 0);
        decomp_kernel<<<dim3(128, 8), 256, 0, stream>>>(
            XEb, encYb, XEb, nullptr, 96, 0);
    }
    ln_rows_kernel<<<12288, 256, 0, stream>>>(XEb, enc_norm_w, enc_norm_b, XEb);
    timesub_kernel<<<dim3(128, 8), 256, 0, stream>>>(XEb, 96);

    // ---- decoder embed (as GEMM; bf16-only output)
    embed_wpack<<<2, 256, 0, stream>>>(dec_emb_conv_w, dec_emb_time_w, Wcb);
    embed_feat<<<72, 256, 0, stream>>>(SI, x_mark_dec, Fb, 144);
    gemm(Fb, Wcb, nullptr, nullptr, XDb, 18432, 512, 64, 64, 64, 0, 0);

    // ---- decoder self fourier block (M=64)
    {
        unsigned short* Pq = (unsigned short*)(SC);
        unsigned short* XT = (unsigned short*)(SC + 4718592);
        unsigned short* WB = (unsigned short*)(SC + 8912896);
        unsigned short* Yp = (unsigned short*)(SC);
        unsigned short* Tidb = (unsigned short*)(SC + 9437184);
        unsigned short* To_b = (unsigned short*)(SC);  // bf16, over dead Yp

        gemm(XDb, ds_qw_b, ds_qb, nullptr, Pq, 18432, 512, 512, 512, 512, 0, 0);
        dft_mfma2<<<dim3(1, 512), 256, 0, stream>>>(Pq, TdbD, XT, 144, 160, 64);
        wtrans3<<<dim3(16, 8), 256, 0, stream>>>(ds_fw, WB, 64);
        mix_v2<<<dim3(64, 8), 256, 0, stream>>>(XT, WB, Yp, 64);
        idft_v2<<<dim3(2, 512), 256, 0, stream>>>(Yp, TibD, Tidb, 144, 128, 64, 1.f / 144.f);
        gemm(Tidb, ds_ow_b, ds_ob, nullptr, To_b, 18432, 512, 512, 512, 512, 0, 0);
        decomp_kernel<<<dim3(128, 8), 256, 0, stream>>>(
            XDb, To_b, XDb, TS, 144, 1);
    }

    // ---- cross attention
    {
        unsigned short* Pq  = (unsigned short*)(SC);
        unsigned short* XTQ = (unsigned short*)(SC + 4718592);
        unsigned short* Pk  = (unsigned short*)(SC);
        unsigned short* XTK = (unsigned short*)(SC + 8912896);
        unsigned* G         = (unsigned*)(SC);
        unsigned short* VT  = (unsigned short*)(SC + 3145728);
        unsigned short* WB  = (unsigned short*)(SC + 7340032);
        unsigned short* Yp  = (unsigned short*)(SC + 11534336);
        unsigned short* Tidb = (unsigned short*)(SC);
        unsigned short* To_b = (unsigned short*)(SC + 4718592);  // bf16, over dead XTQ/VT/WB

        gemm(XDb, dc_qw_b, dc_qb, nullptr, Pq, 18432, 512, 512, 512, 512, 0, 0);
        dft_mfma2<<<dim3(1, 512), 256, 0, stream>>>(Pq, TdbD, XTQ, 144, 160, 64);
        gemm(XEb, dc_kw_b, dc_kb, nullptr, Pk, 12288, 512, 512, 512, 512, 0, 0);
        dft_mfma2<<<dim3(1, 512), 256, 0, stream>>>(Pk, TdbE, XTK, 96, 96, 48);
        xqk3<<<dim3(128, 8), 256, 0, stream>>>(XTQ, XTK, G);
        xqkv3<<<dim3(128, 8), 256, 0, stream>>>(G, XTK, VT);
        wtrans3<<<dim3(16, 8), 256, 0, stream>>>(dc_fw, WB, 64);
        mix_v2<<<dim3(64, 8), 256, 0, stream>>>(VT, WB, Yp, 64);
        idft_v2<<<dim3(2, 512), 256, 0, stream>>>(Yp, TibD, Tidb, 144, 128, 64,
                                                  1.f / (144.f * 262144.f));
        gemm(Tidb, dc_ow_b, dc_ob, nullptr, To_b, 18432, 512, 512, 512, 512, 0, 0);
        decomp_kernel<<<dim3(128, 8), 256, 0, stream>>>(
            XDb, To_b, XDb, TS, 144, 2);
    }

    // ---- decoder FFN: 2 chunks of N=1024; hid bf16 in SC, fout bf16 in XE area
    {
        unsigned short* hid = (unsigned short*)(SC);
        unsigned short* fout_b = (unsigned short*)XE;  // XE fp32 area is scratch
        for (int j0 = 0; j0 < 2048; j0 += 1024) {
            gemm(XDb, dec_c1_b + (size_t)j0 * 512, nullptr, nullptr, hid,
                 18432, 1024, 512, 512, 512, 1, 0);
            gemm(hid, dec_c2_b + j0, nullptr, nullptr, fout_b,
                 18432, 512, 1024, 1024, 2048, 0, j0 > 0);
        }
        decomp_kernel<<<dim3(128, 8), 256, 0, stream>>>(
            XDb, fout_b, XDb, TS, 144, 2);
    }

    // ---- final norm + trend conv + projection
    ln_rows_kernel<<<18432, 256, 0, stream>>>(XDb, dec_norm_w, dec_norm_b, XDb);
    timesub_kernel<<<dim3(128, 8), 256, 0, stream>>>(XDb, 144);
    final_v2<<<12288, 256, 0, stream>>>(
        XDb, TS, TI, dec_trend_w, proj_w, proj_b, (float*)d_out);
}

// Round 11
// 1238.091 us; speedup vs baseline: 1.0821x; 1.0389x over previous
//
#include <hip/hip_runtime.h>
#include <hip/hip_bf16.h>
#include <math.h>

// Model_45904610459674: FEDformer-style forecaster.
// Round 20: R19 (1286 us, best) + ONE lever: bijective XCD-aware block
// swizzle (m204) in gemm_bb ONLY — isolated for the first time (R12 had it
// bundled with pipe+transposed-q). Targets the 3.5x read amplification on
// the big FFN gemms (FETCH 51 MB vs 15 logical): consecutive block IDs
// share an A-panel; remap so they land on one XCD's L2. All gemm grids are
// multiples of 8 blocks -> wgid = (orig%8)*(nwg/8)+orig/8 is bijective.
// Everything else byte-identical to R19 (absmax 0.0117 passing).
// Workspace: 53,768,192 floats = 215.07 MB (same guard).

#define PI_F 3.14159265358979323846f

typedef short bf16x8 __attribute__((ext_vector_type(8)));
typedef float f32x4 __attribute__((ext_vector_type(4)));

static __device__ __forceinline__ int iclamp(int v, int lo, int hi) {
    return v < lo ? lo : (v > hi ? hi : v);
}
static __device__ __forceinline__ unsigned pack2(float x, float y) {
    unsigned xu = __float_as_uint(x) + 0x8000u;
    unsigned yu = __float_as_uint(y) + 0x8000u;
    return (xu >> 16) | (yu & 0xFFFF0000u);
}
static __device__ __forceinline__ unsigned short bfr(float x) {
    return (unsigned short)((__float_as_uint(x) + 0x8000u) >> 16);
}
static __device__ __forceinline__ float bf2f(unsigned short s) {
    return __uint_as_float((unsigned)s << 16);
}

__global__ void zero_out_kernel(float* __restrict__ out, int n) {
    int i = blockIdx.x * 256 + threadIdx.x;
    if (i < n) out[i] = 0.f;
}

// fused fp32->bf16 for all 11 weight tensors in one dispatch.
struct F2BArgs {
    const float* s[11];
    unsigned short* d[11];
    int boff[12];
};
__global__ void f2b_multi(F2BArgs a) {
    int blk = blockIdx.x;
    int seg = 0;
    while (blk >= a.boff[seg + 1]) seg++;  // uniform scalar scan, <=11 iters
    int i = (blk - a.boff[seg]) * 1024 + threadIdx.x * 4;
    const float4 v = *(const float4*)(a.s[seg] + i);
    *(uint2*)(a.d[seg] + i) = make_uint2(pack2(v.x, v.y), pack2(v.z, v.w));
}

// ---------------------------------------------------------------------------
__global__ void preprocess_kernel(const float* __restrict__ xe,
                                  float* __restrict__ SI, float* __restrict__ TI) {
    int idx = blockIdx.x * 256 + threadIdx.x;
    if (idx >= 128 * 144 * 7) return;
    int c = idx % 7;
    int l = (idx / 7) % 144;
    int b = idx / (7 * 144);
    const float* xb = xe + (size_t)b * 96 * 7;
    if (l < 48) {
        int p = 48 + l;
        float sum = 0.f;
        for (int j = -12; j <= 12; j++) sum += xb[iclamp(p + j, 0, 95) * 7 + c];
        float ma = sum * (1.0f / 25.0f);
        SI[idx] = xb[p * 7 + c] - ma;
        TI[idx] = ma;
    } else {
        SI[idx] = 0.f;
        float m = 0.f;
        for (int l2 = 0; l2 < 96; l2++) m += xb[l2 * 7 + c];
        TI[idx] = m * (1.0f / 96.0f);
    }
}

// ---------------------------------------------------------------------------
// Embedding as GEMM: feature matrix F[row][k] bf16, K padded 25->64.
__global__ void embed_feat(const float* __restrict__ x, const float* __restrict__ mark,
                           unsigned short* __restrict__ F, int L) {
    int row = blockIdx.x * 256 + threadIdx.x;
    if (row >= 128 * L) return;
    int l = row % L;
    int b = row / L;
    int lm = (l == 0) ? L - 1 : l - 1;
    int lp = (l == L - 1) ? 0 : l + 1;
    const float* x0 = x + (size_t)b * L * 7;
    const float* mk = mark + (size_t)row * 4;
    union { unsigned short s[64]; uint4 u[8]; } f;
#pragma unroll
    for (int k = 0; k < 8; k++) f.u[k] = make_uint4(0u, 0u, 0u, 0u);
#pragma unroll
    for (int c = 0; c < 7; c++) {
        f.s[c * 3 + 0] = bfr(x0[lm * 7 + c]);
        f.s[c * 3 + 1] = bfr(x0[l * 7 + c]);
        f.s[c * 3 + 2] = bfr(x0[lp * 7 + c]);
    }
#pragma unroll
    for (int j = 0; j < 4; j++) f.s[21 + j] = bfr(mk[j]);
    uint4* dst = (uint4*)(F + (size_t)row * 64);
#pragma unroll
    for (int k = 0; k < 8; k++) dst[k] = f.u[k];
}

// packed embedding weight Wc[o][k] bf16, matching embed_feat's k layout
__global__ void embed_wpack(const float* __restrict__ cw, const float* __restrict__ tw,
                            unsigned short* __restrict__ Wc) {
    int o = blockIdx.x * 256 + threadIdx.x;
    if (o >= 512) return;
    union { unsigned short s[64]; uint4 u[8]; } f;
#pragma unroll
    for (int k = 0; k < 8; k++) f.u[k] = make_uint4(0u, 0u, 0u, 0u);
#pragma unroll
    for (int c = 0; c < 7; c++) {
        const float* w = cw + (o * 7 + c) * 3;
        f.s[c * 3 + 0] = bfr(w[0]);
        f.s[c * 3 + 1] = bfr(w[1]);
        f.s[c * 3 + 2] = bfr(w[2]);
    }
#pragma unroll
    for (int j = 0; j < 4; j++) f.s[21 + j] = bfr(tw[o * 4 + j]);
    uint4* dst = (uint4*)(Wc + (size_t)o * 64);
#pragma unroll
    for (int k = 0; k < 8; k++) dst[k] = f.u[k];
}

// ---------------------------------------------------------------------------
// gemm_bb: A,W bf16. Staging: global_load_lds 16B DMA, XOR-swizzled chunks.
// Bijective XCD swizzle: consecutive orig block IDs (sharing an A-panel)
// map to one XCD's L2 (all grids are multiples of 8 blocks).
// Epilogue (R17 form): Cf (fp32) and/or Cb (bf16); accum reads Cf if
// present, else Cb (bf16 accumulate — dec-FFN chunk sum).
__global__ __launch_bounds__(256, 4) void gemm_bb(
    const unsigned short* __restrict__ A, const unsigned short* __restrict__ W,
    const float* __restrict__ bias, float* __restrict__ Cf,
    unsigned short* __restrict__ Cb,
    int N, int K, int lda, int ldw, int gelu, int accum) {
    __shared__ unsigned short As[128 * 64];
    __shared__ unsigned short Ws[128 * 64];
    const int tid = threadIdx.x;
    const int lane = tid & 63, wv = tid >> 6;
    const int wm = (wv & 1) * 64, wn = (wv >> 1) * 64;
    const int q = lane >> 4, ln = lane & 15;
    // XCD-aware bijective remap (nwg % 8 == 0 for all our grids)
    const int nbx = gridDim.x;
    const int nwg = nbx * gridDim.y;
    const int orig = blockIdx.y * nbx + blockIdx.x;
    const int wgid = (orig & 7) * (nwg >> 3) + (orig >> 3);
    const size_t bm = (size_t)(wgid / nbx) * 128;
    const size_t bn = (size_t)(wgid % nbx) * 128;

    f32x4 acc[4][4];
#pragma unroll
    for (int i = 0; i < 4; i++)
#pragma unroll
        for (int j = 0; j < 4; j++) acc[i][j] = (f32x4){0.f, 0.f, 0.f, 0.f};

    for (int k0 = 0; k0 < K; k0 += 64) {
#pragma unroll
        for (int t = 0; t < 4; t++) {
            int idx = (wv * 4 + t) * 64 + lane;
            int row = idx >> 3, cp = idx & 7;
            int cl = cp ^ (row & 7);
            __builtin_amdgcn_global_load_lds(
                (const __attribute__((address_space(1))) void*)(A + (bm + row) * lda + k0 + cl * 8),
                (__attribute__((address_space(3))) void*)(As + (size_t)(wv * 4 + t) * 512),
                16, 0, 0);
            __builtin_amdgcn_global_load_lds(
                (const __attribute__((address_space(1))) void*)(W + (bn + row) * ldw + k0 + cl * 8),
                (__attribute__((address_space(3))) void*)(Ws + (size_t)(wv * 4 + t) * 512),
                16, 0, 0);
        }
        __syncthreads();
#pragma unroll
        for (int kk = 0; kk < 64; kk += 32) {
            bf16x8 af[4], bfr4[4];
            const int cq = (kk >> 3) + q;
#pragma unroll
            for (int i = 0; i < 4; i++) {
                int r = wm + i * 16 + ln;
                af[i] = *(const bf16x8*)(As + r * 64 + ((cq ^ (r & 7)) * 8));
                int rw = wn + i * 16 + ln;
                bfr4[i] = *(const bf16x8*)(Ws + rw * 64 + ((cq ^ (rw & 7)) * 8));
            }
#pragma unroll
            for (int i = 0; i < 4; i++)
#pragma unroll
                for (int j = 0; j < 4; j++)
                    acc[i][j] = __builtin_amdgcn_mfma_f32_16x16x32_bf16(
                        af[i], bfr4[j], acc[i][j], 0, 0, 0);
        }
        __syncthreads();
    }
#pragma unroll
    for (int j = 0; j < 4; j++) {
        int col = (int)bn + wn + j * 16 + ln;
        float bv = bias ? bias[col] : 0.f;
#pragma unroll
        for (int i = 0; i < 4; i++) {
            size_t row0 = bm + wm + i * 16 + q * 4;
#pragma unroll
            for (int r = 0; r < 4; r++) {
                float v = acc[i][j][r] + bv;
                if (gelu) v = 0.5f * v * (1.f + erff(v * 0.70710678118654752f));
                size_t off = (row0 + r) * N + col;
                if (Cf) {
                    float* p = Cf + off;
                    if (accum) v += *p;
                    *p = v;
                } else if (accum) {
                    v += bf2f(Cb[off]);
                }
                if (Cb) Cb[off] = bfr(v);
            }
        }
    }
}

// ---------------------------------------------------------------------------
// twiddle tables (bf16)
__global__ void dtab_kernel(unsigned short* __restrict__ T, int M, int L, int ldk) {
    int i = blockIdx.x * 256 + threadIdx.x;
    if (i >= 128 * ldk) return;
    int n = i / ldk, k = i - n * ldk;
    float val = 0.f;
    if (n < 2 * M && k < L) {
        int m = n >> 1;
        int r = (m * k) % L;
        float ang = -2.f * PI_F * (float)r / (float)L;
        val = (n & 1) ? sinf(ang) : cosf(ang);
    }
    T[i] = bfr(val);
}
__global__ void itab_kernel(unsigned short* __restrict__ T, int M, int L, int K) {
    int i = blockIdx.x * 256 + threadIdx.x;
    if (i >= L * K) return;
    int n = i / K, k = i - n * K;
    int m = k >> 1;
    float c = (m == 0) ? 1.f : 2.f;
    int r = (m * n) % L;
    float ang = 2.f * PI_F * (float)r / (float)L;
    float val = (k & 1) ? -c * sinf(ang) : c * cosf(ang);
    T[i] = bfr(val);
}

// ---------------------------------------------------------------------------
// dft MFMA v2 (bf16 input): P bf16 [B*L,512] -> XT[h][m][b][2e+p] bf16
__global__ __launch_bounds__(256) void dft_mfma2(
    const unsigned short* __restrict__ P, const unsigned short* __restrict__ Tdb,
    unsigned short* __restrict__ XT, int L, int ldk, int M) {
    __shared__ unsigned short tile[128 * 130];
    const int tid = threadIdx.x;
    const int lane = tid & 63, wv = tid >> 6;
    const int wm = (wv & 1) * 64, wn = (wv >> 1) * 64;
    const int q = lane >> 4, ln = lane & 15;
    const int bm = blockIdx.y;
    const int b = bm >> 2, c0 = (bm & 3) * 128;
    const int h0 = c0 >> 6;
    const unsigned short* Pb = P + (size_t)b * L * 512;

    f32x4 acc[4][4];
#pragma unroll
    for (int i = 0; i < 4; i++)
#pragma unroll
        for (int j = 0; j < 4; j++) acc[i][j] = (f32x4){0.f, 0.f, 0.f, 0.f};

    for (int k0 = 0; k0 < L; k0 += 32) {
        bf16x8 af[4], bf[4];
        union FR { bf16x8 v; unsigned short s[8]; };
#pragma unroll
        for (int i = 0; i < 4; i++) {
            int c = c0 + wm + i * 16 + ln;
            FR fr;
#pragma unroll
            for (int t = 0; t < 8; t++) {
                int l = k0 + q * 8 + t;
                fr.s[t] = (l < L) ? Pb[(size_t)l * 512 + c] : (unsigned short)0;
            }
            af[i] = fr.v;
        }
#pragma unroll
        for (int j = 0; j < 4; j++) {
            int n = wn + j * 16 + ln;
            bf[j] = *(const bf16x8*)(Tdb + (size_t)n * ldk + k0 + q * 8);
        }
#pragma unroll
        for (int i = 0; i < 4; i++)
#pragma unroll
            for (int j = 0; j < 4; j++)
                acc[i][j] = __builtin_amdgcn_mfma_f32_16x16x32_bf16(
                    af[i], bf[j], acc[i][j], 0, 0, 0);
    }
#pragma unroll
    for (int j = 0; j < 4; j++) {
        int col = wn + j * 16 + ln;
#pragma unroll
        for (int i = 0; i < 4; i++) {
            int r0 = wm + i * 16 + q * 4;
#pragma unroll
            for (int r = 0; r < 4; r++)
                tile[(r0 + r) * 130 + col] = bfr(acc[i][j][r]);
        }
    }
    __syncthreads();
    unsigned* XTu = (unsigned*)XT;
    for (int idx = tid; idx < 2 * M * 64; idx += 256) {
        int chunk = idx >> 6, e = idx & 63;
        int h2 = chunk / M, m = chunk - h2 * M;
        unsigned v = *(const unsigned*)&tile[(h2 * 64 + e) * 130 + 2 * m];
        XTu[((size_t)((h0 + h2) * M + m) * 128 + b) * 64 + e] = v;
    }
}

// ---------------------------------------------------------------------------
// wtrans3: w[h][e][o][m][2] fp32 -> WB[(h*M+m)][n=2o+q][k=2e+p] bf16
__global__ __launch_bounds__(256) void wtrans3(
    const float* __restrict__ w, unsigned short* __restrict__ WB, int M) {
    __shared__ float Lre[16 * 289], Lim[16 * 289];
    const int h = blockIdx.y;
    const int ot = blockIdx.x >> 1, et = blockIdx.x & 1;
    const int o0 = ot * 8, e0 = et * 32;
    const int tid = threadIdx.x;
    unsigned* WBu = (unsigned*)WB;
    for (int mc = 0; mc < M; mc += 16) {
        for (int idx = tid; idx < 4096; idx += 256) {
            int e = idx >> 7, o = (idx >> 4) & 7, mm = idx & 15;
            const float2 v = *(const float2*)(
                w + ((((size_t)h * 64 + e0 + e) * 64 + o0 + o) * M + mc + mm) * 2);
            Lre[mm * 289 + e * 9 + o] = v.x;
            Lim[mm * 289 + e * 9 + o] = v.y;
        }
        __syncthreads();
        for (int widx = tid; widx < 8192; widx += 256) {
            int mm = widx >> 9, no = (widx >> 5) & 15, e = widx & 31;
            int ol = no >> 1, qn = no & 1;
            float re = Lre[mm * 289 + e * 9 + ol];
            float im = Lim[mm * 289 + e * 9 + ol];
            unsigned v = qn ? pack2(im, re) : pack2(re, -im);
            WBu[((size_t)(h * M + mc + mm) * 128 + 2 * (o0 + ol) + qn) * 64 + e0 + e] = v;
        }
        __syncthreads();
    }
}

// ---------------------------------------------------------------------------
// mix_v2: per (h,m): Y'[b][n] = sum_k XT[hm][b][k]*WB[hm][n][k], b128 loads
__global__ __launch_bounds__(256) void mix_v2(
    const unsigned short* __restrict__ XT, const unsigned short* __restrict__ WB,
    unsigned short* __restrict__ Yp, int M) {
    __shared__ unsigned short tile[128 * 130];
    const int m = blockIdx.x, h = blockIdx.y;
    const int tid = threadIdx.x;
    const int lane = tid & 63, wv = tid >> 6;
    const int wm = (wv & 1) * 64, wn = (wv >> 1) * 64;
    const int q = lane >> 4, ln = lane & 15;
    const size_t hm = (size_t)h * M + m;
    const unsigned short* Ab = XT + hm * 16384;
    const unsigned short* Bb = WB + hm * 16384;

    f32x4 acc[4][4];
#pragma unroll
    for (int i = 0; i < 4; i++)
#pragma unroll
        for (int j = 0; j < 4; j++) acc[i][j] = (f32x4){0.f, 0.f, 0.f, 0.f};

#pragma unroll
    for (int k0 = 0; k0 < 128; k0 += 32) {
        bf16x8 af[4], bf[4];
#pragma unroll
        for (int i = 0; i < 4; i++)
            af[i] = *(const bf16x8*)(Ab + (size_t)(wm + i * 16 + ln) * 128 + k0 + q * 8);
#pragma unroll
        for (int j = 0; j < 4; j++)
            bf[j] = *(const bf16x8*)(Bb + (size_t)(wn + j * 16 + ln) * 128 + k0 + q * 8);
#pragma unroll
        for (int i = 0; i < 4; i++)
#pragma unroll
            for (int j = 0; j < 4; j++)
                acc[i][j] = __builtin_amdgcn_mfma_f32_16x16x32_bf16(
                    af[i], bf[j], acc[i][j], 0, 0, 0);
    }
#pragma unroll
    for (int j = 0; j < 4; j++) {
        int col = wn + j * 16 + ln;
#pragma unroll
        for (int i = 0; i < 4; i++) {
            int r0 = wm + i * 16 + q * 4;
#pragma unroll
            for (int r = 0; r < 4; r++)
                tile[(r0 + r) * 130 + col] = bfr(acc[i][j][r]);
        }
    }
    __syncthreads();
    unsigned* Yu = (unsigned*)Yp;
    for (int idx = tid; idx < 128 * 64; idx += 256) {
        int b = idx >> 6, dw = idx & 63;
        unsigned v = *(const unsigned*)&tile[b * 130 + 2 * dw];
        Yu[(hm * 128 + b) * 64 + dw] = v;
    }
}

// ---------------------------------------------------------------------------
// idft_v2: Out bf16 [(b,h,o)*L + l] = bf16(s * sum_k Y'[..][k]*Ti[l][k])
__global__ __launch_bounds__(256) void idft_v2(
    const unsigned short* __restrict__ Yp, const unsigned short* __restrict__ Tib,
    unsigned short* __restrict__ Out, int L, int K, int M, float s) {
    __shared__ unsigned short sh[2 * 64 * 132];
    const int tid = threadIdx.x;
    const int lane = tid & 63, wv = tid >> 6;
    const int wm = (wv & 1) * 64, wn = (wv >> 1) * 64;
    const int q = lane >> 4, ln = lane & 15;
    const int bm = blockIdx.y;
    const int b = bm >> 2, h0 = (bm & 3) * 2;
    const int bn = blockIdx.x * 128;

    const unsigned* Yu = (const unsigned*)Yp;
    for (int idx = tid; idx < 2 * M * 64; idx += 256) {
        int chunk = idx >> 6, dw = idx & 63;
        int h2 = chunk / M, m = chunk - h2 * M;
        unsigned v = Yu[((size_t)((h0 + h2) * M + m) * 128 + b) * 64 + dw];
        *(unsigned*)&sh[chunk * 132 + 2 * dw] = v;
    }
    __syncthreads();

    f32x4 acc[4][4];
#pragma unroll
    for (int i = 0; i < 4; i++)
#pragma unroll
        for (int j = 0; j < 4; j++) acc[i][j] = (f32x4){0.f, 0.f, 0.f, 0.f};

    for (int k0 = 0; k0 < K; k0 += 32) {
        bf16x8 af[4], bf[4];
        union FR { bf16x8 v; unsigned u[4]; };
#pragma unroll
        for (int i = 0; i < 4; i++) {
            int lr = wm + i * 16 + ln;
            int h2 = lr >> 6, o = lr & 63;
            FR fr;
#pragma unroll
            for (int jj = 0; jj < 4; jj++) {
                int m = (k0 >> 1) + q * 4 + jj;
                fr.u[jj] = *(const unsigned*)&sh[(h2 * M + m) * 132 + 2 * o];
            }
            af[i] = fr.v;
        }
#pragma unroll
        for (int j = 0; j < 4; j++) {
            int n = bn + wn + j * 16 + ln;
            if (n < L) bf[j] = *(const bf16x8*)(Tib + (size_t)n * K + k0 + q * 8);
            else bf[j] = (bf16x8){0, 0, 0, 0, 0, 0, 0, 0};
        }
#pragma unroll
        for (int i = 0; i < 4; i++)
#pragma unroll
            for (int j = 0; j < 4; j++)
                acc[i][j] = __builtin_amdgcn_mfma_f32_16x16x32_bf16(
                    af[i], bf[j], acc[i][j], 0, 0, 0);
    }
#pragma unroll
    for (int j = 0; j < 4; j++) {
        int col = bn + wn + j * 16 + ln;
        if (col >= L) continue;
#pragma unroll
        for (int i = 0; i < 4; i++) {
            int row0 = bm * 128 + wm + i * 16 + q * 4;
#pragma unroll
            for (int r = 0; r < 4; r++)
                Out[(size_t)(row0 + r) * L + col] = bfr(acc[i][j][r] * s);
        }
    }
}

// ---------------------------------------------------------------------------
// xqk3: per (b,h): S = Q^T [Kre|Kim] via 64x96x128 bf16 MFMA, tanh -> G.
__global__ __launch_bounds__(256) void xqk3(
    const unsigned short* __restrict__ XTQ, const unsigned short* __restrict__ XTK,
    unsigned* __restrict__ G) {
    __shared__ __align__(16) unsigned char sm[43520];
    unsigned short* Qs = (unsigned short*)sm;            // [64][136]
    unsigned short* Bs = (unsigned short*)(sm + 17408);  // [96][136]
    float* Ss = (float*)sm;                              // [64][100] alias
    const int b = blockIdx.x, h = blockIdx.y;
    const int tid = threadIdx.x;
    const int lane = tid & 63, wv = tid >> 6;
    const int wm = (wv & 1) * 32, wn = (wv >> 1) * 48;
    const int q = lane >> 4, ln = lane & 15;

    const uint4* Qg = (const uint4*)XTQ;
    for (int i = tid; i < 64 * 16; i += 256) {
        int x = i >> 4, c = i & 15;
        *(uint4*)(Qs + x * 136 + c * 8) = Qg[((size_t)(h * 64 + x) * 128 + b) * 16 + c];
    }
    const unsigned* Ku = (const unsigned*)XTK;
    unsigned* Bu = (unsigned*)Bs;
    for (int i = tid; i < 48 * 64; i += 256) {
        int y = i >> 6, e = i & 63;
        unsigned v = Ku[((size_t)(h * 48 + y) * 128 + b) * 64 + e];
        Bu[y * 68 + e] = v ^ 0x80000000u;
        Bu[(48 + y) * 68 + e] = (v >> 16) | (v << 16);
    }
    __syncthreads();

    f32x4 acc[2][3];
#pragma unroll
    for (int i = 0; i < 2; i++)
#pragma unroll
        for (int j = 0; j < 3; j++) acc[i][j] = (f32x4){0.f, 0.f, 0.f, 0.f};

#pragma unroll
    for (int k0 = 0; k0 < 128; k0 += 32) {
        bf16x8 af[2], bf[3];
#pragma unroll
        for (int i = 0; i < 2; i++)
            af[i] = *(const bf16x8*)(Qs + (wm + i * 16 + ln) * 136 + k0 + q * 8);
#pragma unroll
        for (int j = 0; j < 3; j++)
            bf[j] = *(const bf16x8*)(Bs + (wn + j * 16 + ln) * 136 + k0 + q * 8);
#pragma unroll
        for (int i = 0; i < 2; i++)
#pragma unroll
            for (int j = 0; j < 3; j++)
                acc[i][j] = __builtin_amdgcn_mfma_f32_16x16x32_bf16(
                    af[i], bf[j], acc[i][j], 0, 0, 0);
    }
    __syncthreads();   // safe to alias Ss over Qs/Bs
#pragma unroll
    for (int j = 0; j < 3; j++) {
        int col = wn + j * 16 + ln;
#pragma unroll
        for (int i = 0; i < 2; i++) {
            int r0 = wm + i * 16 + q * 4;
#pragma unroll
            for (int r = 0; r < 4; r++)
                Ss[(r0 + r) * 100 + col] = acc[i][j][r];
        }
    }
    __syncthreads();
    for (int i = tid; i < 3072; i += 256) {
        int x = i / 48, y = i - x * 48;
        float re = Ss[x * 100 + y], im = Ss[x * 100 + 48 + y];
        float a2 = 2.f * re, b2 = 2.f * im;
        a2 = fminf(fmaxf(a2, -80.f), 80.f);
        float denom = coshf(a2) + cosf(b2);
        G[((size_t)(b * 8 + h) * 64 + x) * 48 + y] =
            pack2(sinhf(a2) / denom, sinf(b2) / denom);
    }
}

// ---------------------------------------------------------------------------
// xqkv3: per (b,h): V = G · B2 via 64x128x96 bf16 MFMA.
__global__ __launch_bounds__(256) void xqkv3(
    const unsigned* __restrict__ G, const unsigned short* __restrict__ XTK,
    unsigned short* __restrict__ VT) {
    __shared__ __align__(16) unsigned char sm[26624];
    unsigned short* Bs = (unsigned short*)sm;   // [128][104]
    unsigned short* Vs = (unsigned short*)sm;   // [64][132] alias after MFMA
    const int b = blockIdx.x, h = blockIdx.y;
    const int tid = threadIdx.x;
    const int lane = tid & 63, wv = tid >> 6;
    const int wm = (wv & 1) * 32, wn = (wv >> 1) * 64;
    const int q = lane >> 4, ln = lane & 15;

    const unsigned* Ku = (const unsigned*)XTK;
    unsigned* Bu = (unsigned*)Bs;
    for (int i = tid; i < 48 * 64; i += 256) {
        int y = i >> 6, e = i & 63;
        unsigned v = Ku[((size_t)(h * 48 + y) * 128 + b) * 64 + e];
        Bu[(2 * e) * 52 + y] = v ^ 0x80000000u;          // (kr,-ki)
        Bu[(2 * e + 1) * 52 + y] = (v >> 16) | (v << 16); // (ki,kr)
    }
    __syncthreads();

    const unsigned short* Ag = (const unsigned short*)G + (size_t)(b * 8 + h) * 6144;
    f32x4 acc[2][4];
#pragma unroll
    for (int i = 0; i < 2; i++)
#pragma unroll
        for (int j = 0; j < 4; j++) acc[i][j] = (f32x4){0.f, 0.f, 0.f, 0.f};

#pragma unroll
    for (int k0 = 0; k0 < 96; k0 += 32) {
        bf16x8 af[2], bf[4];
#pragma unroll
        for (int i = 0; i < 2; i++)
            af[i] = *(const bf16x8*)(Ag + (wm + i * 16 + ln) * 96 + k0 + q * 8);
#pragma unroll
        for (int j = 0; j < 4; j++)
            bf[j] = *(const bf16x8*)(Bs + (wn + j * 16 + ln) * 104 + k0 + q * 8);
#pragma unroll
        for (int i = 0; i < 2; i++)
#pragma unroll
            for (int j = 0; j < 4; j++)
                acc[i][j] = __builtin_amdgcn_mfma_f32_16x16x32_bf16(
                    af[i], bf[j], acc[i][j], 0, 0, 0);
    }
    __syncthreads();   // alias Vs over Bs
#pragma unroll
    for (int j = 0; j < 4; j++) {
        int col = wn + j * 16 + ln;
#pragma unroll
        for (int i = 0; i < 2; i++) {
            int r0 = wm + i * 16 + q * 4;
#pragma unroll
            for (int r = 0; r < 4; r++)
                Vs[(r0 + r) * 132 + col] = bfr(acc[i][j][r]);
        }
    }
    __syncthreads();
    unsigned* Vu = (unsigned*)VT;
    for (int i = tid; i < 64 * 64; i += 256) {
        int x = i >> 6, dw = i & 63;
        Vu[((size_t)(h * 64 + x) * 128 + b) * 64 + dw] = *(unsigned*)&Vs[x * 132 + 2 * dw];
    }
}

// ---------------------------------------------------------------------------
// series_decomp v4: bf16-only residual stream. Pb/Qb bf16 in, SOb bf16 out
// (in-place on Pb safe). TS stays fp32. Sliding-window MA, inline writes.
__global__ void decomp_kernel(const unsigned short* __restrict__ Pb,
                              const unsigned short* __restrict__ Qb,
                              unsigned short* __restrict__ SOb,
                              float* __restrict__ TS, int L, int tmode) {
    int b = blockIdx.x, d0 = blockIdx.y * 64;
    __shared__ float s[144 * 64];
    const int nvec = L * 16;  // 4-elem chunks per row of 64
    for (int i = threadIdx.x; i < nvec; i += 256) {
        int l = i >> 4, c = i & 15;
        size_t gidx = ((size_t)b * L + l) * 512 + d0 + c * 4;
        ushort4 pv = *(const ushort4*)(Pb + gidx);
        float4 v = make_float4(bf2f(pv.x), bf2f(pv.y), bf2f(pv.z), bf2f(pv.w));
        if (Qb) {
            ushort4 qv = *(const ushort4*)(Qb + gidx);
            v.x += bf2f(qv.x); v.y += bf2f(qv.y);
            v.z += bf2f(qv.z); v.w += bf2f(qv.w);
        }
        *(float4*)(s + (size_t)i * 4) = v;
    }
    __syncthreads();
    {
        int d = threadIdx.x & 63, seg = threadIdx.x >> 6;
        int segLen = L >> 2;  // L = 96 or 144, both divisible by 4
        int l0 = seg * segLen;
        float S = 0.f;
#pragma unroll
        for (int j = -12; j <= 12; j++) S += s[iclamp(l0 + j, 0, L - 1) * 64 + d];
        for (int l = l0; l < l0 + segLen; l++) {
            float ma = S * (1.0f / 25.0f);
            float so = s[l * 64 + d] - ma;
            size_t idx = ((size_t)b * L + l) * 512 + d0 + d;
            SOb[idx] = bfr(so);
            if (tmode == 1) TS[idx] = ma;
            else if (tmode == 2) TS[idx] += ma;
            S += s[iclamp(l + 13, 0, L - 1) * 64 + d]
               - s[iclamp(l - 12, 0, L - 1) * 64 + d];
        }
    }
}

// ---------------------------------------------------------------------------
// ln_rows bf16 in/out (in-place safe)
__global__ __launch_bounds__(256) void ln_rows_kernel(
    const unsigned short* __restrict__ in, const float* __restrict__ w,
    const float* __restrict__ bvec, unsigned short* __restrict__ out) {
    size_t row = blockIdx.x;
    const unsigned short* p = in + row * 512;
    int t = threadIdx.x;
    float v0 = bf2f(p[t]), v1 = bf2f(p[t + 256]);
    float s = v0 + v1, s2 = v0 * v0 + v1 * v1;
    for (int o = 32; o > 0; o >>= 1) {
        s += __shfl_xor(s, o, 64);
        s2 += __shfl_xor(s2, o, 64);
    }
    __shared__ float rs[4], rs2[4];
    int wid = t >> 6;
    if ((t & 63) == 0) { rs[wid] = s; rs2[wid] = s2; }
    __syncthreads();
    s = rs[0] + rs[1] + rs[2] + rs[3];
    s2 = rs2[0] + rs2[1] + rs2[2] + rs2[3];
    float mu = s * (1.0f / 512.0f);
    float var = s2 * (1.0f / 512.0f) - mu * mu;
    float r = rsqrtf(var + 1e-5f);
    out[row * 512 + t] = bfr((v0 - mu) * r * w[t] + bvec[t]);
    out[row * 512 + t + 256] = bfr((v1 - mu) * r * w[t + 256] + bvec[t + 256]);
}

// timesub bf16 in-place
__global__ void timesub_kernel(unsigned short* __restrict__ X, int L) {
    int b = blockIdx.x, d0 = blockIdx.y * 64;
    __shared__ float tile[144 * 64];
    __shared__ float mean[64];
    for (int i = threadIdx.x; i < L * 64; i += 256) {
        int l = i >> 6, d = i & 63;
        tile[i] = bf2f(X[((size_t)b * L + l) * 512 + d0 + d]);
    }
    __syncthreads();
    if (threadIdx.x < 64) {
        float sm = 0.f;
        for (int l = 0; l < L; l++) sm += tile[l * 64 + threadIdx.x];
        mean[threadIdx.x] = sm / (float)L;
    }
    __syncthreads();
    for (int i = threadIdx.x; i < L * 64; i += 256) {
        int l = i >> 6, d = i & 63;
        X[((size_t)b * L + l) * 512 + d0 + d] = bfr(tile[i] - mean[d]);
    }
}

// ---------------------------------------------------------------------------
__global__ __launch_bounds__(256) void final_v2(
    const unsigned short* __restrict__ XLb, const float* __restrict__ TS,
    const float* __restrict__ TI, const float* __restrict__ trend_w,
    const float* __restrict__ proj_w, const float* __restrict__ proj_b,
    float* __restrict__ out) {
    int blk = blockIdx.x;
    int b = blk / 96, lo = blk - b * 96;
    int l = lo + 48;
    int lm = l - 1;
    int lp = (l == 143) ? 0 : l + 1;
    const float* ts = TS + (size_t)b * 144 * 512;
    const float* r0 = ts + (size_t)lm * 512;
    const float* r1 = ts + (size_t)l * 512;
    const float* r2 = ts + (size_t)lp * 512;
    const unsigned short* xl = XLb + ((size_t)b * 144 + l) * 512;
    int t = threadIdx.x;
    float p[7];
#pragma unroll
    for (int c = 0; c < 7; c++) p[c] = 0.f;
#pragma unroll
    for (int dd = 0; dd < 2; dd++) {
        int d = t + dd * 256;
        float a0 = r0[d], a1 = r1[d], a2 = r2[d], x = bf2f(xl[d]);
#pragma unroll
        for (int c = 0; c < 7; c++) {
            const float* tw = trend_w + ((size_t)c * 512 + d) * 3;
            float v = a0 * tw[0] + a1 * tw[1] + a2 * tw[2];
            v = fmaf(x, proj_w[c * 512 + d], v);
            p[c] += v;
        }
    }
#pragma unroll
    for (int o = 32; o > 0; o >>= 1)
#pragma unroll
        for (int c = 0; c < 7; c++) p[c] += __shfl_xor(p[c], o, 64);
    __shared__ float red[4][7];
    int wid = t >> 6;
    if ((t & 63) == 0)
#pragma unroll
        for (int c = 0; c < 7; c++) red[wid][c] = p[c];
    __syncthreads();
    if (t < 7) {
        float v = red[0][t] + red[1][t] + red[2][t] + red[3][t]
                + TI[((size_t)b * 144 + l) * 7 + t] + proj_b[t];
        out[(size_t)blk * 7 + t] = v;
    }
}

// ---------------------------------------------------------------------------
static inline int cdiv(int a, int b) { return (a + b - 1) / b; }

extern "C" void kernel_launch(void* const* d_in, const int* in_sizes, int n_in,
                              void* d_out, int out_size, void* d_ws, size_t ws_size,
                              hipStream_t stream) {
    const float* x_enc      = (const float*)d_in[0];
    const float* x_mark_enc = (const float*)d_in[1];
    const float* x_mark_dec = (const float*)d_in[3];
    const float* enc_emb_conv_w = (const float*)d_in[4];
    const float* enc_emb_time_w = (const float*)d_in[5];
    const float* dec_emb_conv_w = (const float*)d_in[6];
    const float* dec_emb_time_w = (const float*)d_in[7];
    const float* enc_qw = (const float*)d_in[8];
    const float* enc_qb = (const float*)d_in[9];
    const float* enc_ow = (const float*)d_in[14];
    const float* enc_ob = (const float*)d_in[15];
    const float* enc_fw = (const float*)d_in[16];
    const float* enc_c1 = (const float*)d_in[17];
    const float* enc_c2 = (const float*)d_in[18];
    const float* enc_norm_w = (const float*)d_in[19];
    const float* enc_norm_b = (const float*)d_in[20];
    const float* ds_qw = (const float*)d_in[21];
    const float* ds_qb = (const float*)d_in[22];
    const float* ds_ow = (const float*)d_in[27];
    const float* ds_ob = (const float*)d_in[28];
    const float* ds_fw = (const float*)d_in[29];
    const float* dc_qw = (const float*)d_in[30];
    const float* dc_qb = (const float*)d_in[31];
    const float* dc_kw = (const float*)d_in[32];
    const float* dc_kb = (const float*)d_in[33];
    const float* dc_ow = (const float*)d_in[36];
    const float* dc_ob = (const float*)d_in[37];
    const float* dc_fw = (const float*)d_in[38];
    const float* dec_c1 = (const float*)d_in[39];
    const float* dec_c2 = (const float*)d_in[40];
    const float* dec_trend_w = (const float*)d_in[41];
    const float* dec_norm_w = (const float*)d_in[42];
    const float* dec_norm_b = (const float*)d_in[43];
    const float* proj_w = (const float*)d_in[44];
    const float* proj_b = (const float*)d_in[45];

    float* ws = (float*)d_ws;
    float* XD   = ws;            // fp32 area now scratch only
    float* TS   = ws + 9437184;
    float* XE   = ws + 18874368; // fp32 area now scratch only
    unsigned short* XEb = (unsigned short*)(ws + 25165824);
    unsigned short* XDb = (unsigned short*)(ws + 28311552);
    float* SI   = ws + 33030144;
    float* TI   = ws + 33159168;
    float* TAB  = ws + 33288192;
    unsigned short* WF = (unsigned short*)(ws + 33320960);
    float* SC   = ws + 37646336;
    unsigned short* TdbE = (unsigned short*)(TAB);
    unsigned short* TdbD = (unsigned short*)(TAB + 6144);
    unsigned short* TibE = (unsigned short*)(TAB + 16384);
    unsigned short* TibD = (unsigned short*)(TAB + 20992);
    unsigned short* Fb  = (unsigned short*)(ws + 51277824);  // up to 18432*64 bf16
    unsigned short* Wcb = (unsigned short*)(ws + 51867648);  // 512*64 bf16

    unsigned short* enc_qw_b = WF;
    unsigned short* enc_ow_b = WF + 524288;
    unsigned short* enc_c1_b = WF + 1048576;
    unsigned short* enc_c2_b = WF + 3145728;
    unsigned short* ds_qw_b  = WF + 5242880;
    unsigned short* ds_ow_b  = WF + 5505024;
    unsigned short* dc_qw_b  = WF + 5767168;
    unsigned short* dc_kw_b  = WF + 6029312;
    unsigned short* dc_ow_b  = WF + 6291456;
    unsigned short* dec_c1_b = WF + 6553600;
    unsigned short* dec_c2_b = WF + 7602176;

    const size_t need_bytes = (size_t)53768192 * sizeof(float);
    if (ws_size < need_bytes) {
        zero_out_kernel<<<cdiv(out_size, 256), 256, 0, stream>>>((float*)d_out, out_size);
        return;
    }

    auto gemm = [&](const unsigned short* A, const unsigned short* W, const float* bias,
                    float* Cf, unsigned short* Cb, int rows, int N, int K,
                    int lda, int ldw, int gelu, int accum) {
        dim3 g(N / 128, rows / 128);
        gemm_bb<<<g, 256, 0, stream>>>(A, W, bias, Cf, Cb, N, K, lda, ldw, gelu, accum);
    };

    // ---- weight conversion (single fused dispatch)
    {
        F2BArgs fa;
        const float* srcs[11] = {enc_qw, enc_ow, enc_c1, enc_c2, ds_qw, ds_ow,
                                 dc_qw, dc_kw, dc_ow, dec_c1, dec_c2};
        unsigned short* dsts[11] = {enc_qw_b, enc_ow_b, enc_c1_b, enc_c2_b, ds_qw_b,
                                    ds_ow_b, dc_qw_b, dc_kw_b, dc_ow_b, dec_c1_b, dec_c2_b};
        const int ns[11] = {524288, 524288, 2097152, 2097152, 262144, 262144,
                            262144, 262144, 262144, 1048576, 1048576};
        int off = 0;
        fa.boff[0] = 0;
        for (int i = 0; i < 11; i++) {
            fa.s[i] = srcs[i];
            fa.d[i] = dsts[i];
            off += ns[i] / 1024;
            fa.boff[i + 1] = off;
        }
        f2b_multi<<<off, 256, 0, stream>>>(fa);
    }

    // ---- twiddle tables
    dtab_kernel<<<cdiv(128 * 96, 256), 256, 0, stream>>>(TdbE, 48, 96, 96);
    dtab_kernel<<<cdiv(128 * 160, 256), 256, 0, stream>>>(TdbD, 64, 144, 160);
    itab_kernel<<<cdiv(96 * 96, 256), 256, 0, stream>>>(TibE, 48, 96, 96);
    itab_kernel<<<cdiv(144 * 128, 256), 256, 0, stream>>>(TibD, 64, 144, 128);

    // ---- preprocess + encoder embed (as GEMM; bf16-only output)
    preprocess_kernel<<<cdiv(128 * 144 * 7, 256), 256, 0, stream>>>(x_enc, SI, TI);
    embed_wpack<<<2, 256, 0, stream>>>(enc_emb_conv_w, enc_emb_time_w, Wcb);
    embed_feat<<<48, 256, 0, stream>>>(x_enc, x_mark_enc, Fb, 96);
    gemm(Fb, Wcb, nullptr, nullptr, XEb, 12288, 512, 64, 64, 64, 0, 0);

    // ---- encoder layers (M=48)
    for (int l = 0; l < 2; l++) {
        const unsigned short* qwb = enc_qw_b + (size_t)l * 262144;
        const float* qb = enc_qb + (size_t)l * 512;
        const unsigned short* owb = enc_ow_b + (size_t)l * 262144;
        const float* ob = enc_ob + (size_t)l * 512;
        const float* fw = enc_fw + (size_t)l * 8 * 64 * 64 * 48 * 2;
        const unsigned short* c1b = enc_c1_b + (size_t)l * 1048576;
        const unsigned short* c2b = enc_c2_b + (size_t)l * 1048576;
        unsigned short* Pq = (unsigned short*)(SC);
        unsigned short* XT = (unsigned short*)(SC + 3145728);
        unsigned short* WB = (unsigned short*)(SC + 6291456);
        unsigned short* Yp = (unsigned short*)(SC + 9437184);
        unsigned short* Tidb = (unsigned short*)(SC);
        unsigned short* To_b = (unsigned short*)(SC + 3145728);  // bf16, over dead XT
        unsigned short* encYb = XDb;  // enc c2 bf16 scratch (XDb unused in encoder)

        gemm(XEb, qwb, qb, nullptr, Pq, 12288, 512, 512, 512, 512, 0, 0);
        dft_mfma2<<<dim3(1, 512), 256, 0, stream>>>(Pq, TdbE, XT, 96, 96, 48);
        wtrans3<<<dim3(16, 8), 256, 0, stream>>>(fw, WB, 48);
        mix_v2<<<dim3(48, 8), 256, 0, stream>>>(XT, WB, Yp, 48);
        idft_v2<<<dim3(1, 512), 256, 0, stream>>>(Yp, TibE, Tidb, 96, 96, 48, 1.f / 96.f);
        gemm(Tidb, owb, ob, nullptr, To_b, 12288, 512, 512, 512, 512, 0, 0);
        decomp_kernel<<<dim3(128, 8), 256, 0, stream>>>(
            XEb, To_b, XEb, nullptr, 96, 0);
        unsigned short* hid = (unsigned short*)(SC);
        gemm(XEb, c1b, nullptr, nullptr, hid, 12288, 2048, 512, 512, 512, 1, 0);
        gemm(hid, c2b, nullptr, nullptr, encYb, 12288, 512, 2048, 2048, 2048, 0, 0);
        decomp_kernel<<<dim3(128, 8), 256, 0, stream>>>(
            XEb, encYb, XEb, nullptr, 96, 0);
    }
    ln_rows_kernel<<<12288, 256, 0, stream>>>(XEb, enc_norm_w, enc_norm_b, XEb);
    timesub_kernel<<<dim3(128, 8), 256, 0, stream>>>(XEb, 96);

    // ---- decoder embed (as GEMM; bf16-only output)
    embed_wpack<<<2, 256, 0, stream>>>(dec_emb_conv_w, dec_emb_time_w, Wcb);
    embed_feat<<<72, 256, 0, stream>>>(SI, x_mark_dec, Fb, 144);
    gemm(Fb, Wcb, nullptr, nullptr, XDb, 18432, 512, 64, 64, 64, 0, 0);

    // ---- decoder self fourier block (M=64)
    {
        unsigned short* Pq = (unsigned short*)(SC);
        unsigned short* XT = (unsigned short*)(SC + 4718592);
        unsigned short* WB = (unsigned short*)(SC + 8912896);
        unsigned short* Yp = (unsigned short*)(SC);
        unsigned short* Tidb = (unsigned short*)(SC + 9437184);
        unsigned short* To_b = (unsigned short*)(SC);  // bf16, over dead Yp

        gemm(XDb, ds_qw_b, ds_qb, nullptr, Pq, 18432, 512, 512, 512, 512, 0, 0);
        dft_mfma2<<<dim3(1, 512), 256, 0, stream>>>(Pq, TdbD, XT, 144, 160, 64);
        wtrans3<<<dim3(16, 8), 256, 0, stream>>>(ds_fw, WB, 64);
        mix_v2<<<dim3(64, 8), 256, 0, stream>>>(XT, WB, Yp, 64);
        idft_v2<<<dim3(2, 512), 256, 0, stream>>>(Yp, TibD, Tidb, 144, 128, 64, 1.f / 144.f);
        gemm(Tidb, ds_ow_b, ds_ob, nullptr, To_b, 18432, 512, 512, 512, 512, 0, 0);
        decomp_kernel<<<dim3(128, 8), 256, 0, stream>>>(
            XDb, To_b, XDb, TS, 144, 1);
    }

    // ---- cross attention
    {
        unsigned short* Pq  = (unsigned short*)(SC);
        unsigned short* XTQ = (unsigned short*)(SC + 4718592);
        unsigned short* Pk  = (unsigned short*)(SC);
        unsigned short* XTK = (unsigned short*)(SC + 8912896);
        unsigned* G         = (unsigned*)(SC);
        unsigned short* VT  = (unsigned short*)(SC + 3145728);
        unsigned short* WB  = (unsigned short*)(SC + 7340032);
        unsigned short* Yp  = (unsigned short*)(SC + 11534336);
        unsigned short* Tidb = (unsigned short*)(SC);
        unsigned short* To_b = (unsigned short*)(SC + 4718592);  // bf16, over dead XTQ/VT/WB

        gemm(XDb, dc_qw_b, dc_qb, nullptr, Pq, 18432, 512, 512, 512, 512, 0, 0);
        dft_mfma2<<<dim3(1, 512), 256, 0, stream>>>(Pq, TdbD, XTQ, 144, 160, 64);
        gemm(XEb, dc_kw_b, dc_kb, nullptr, Pk, 12288, 512, 512, 512, 512, 0, 0);
        dft_mfma2<<<dim3(1, 512), 256, 0, stream>>>(Pk, TdbE, XTK, 96, 96, 48);
        xqk3<<<dim3(128, 8), 256, 0, stream>>>(XTQ, XTK, G);
        xqkv3<<<dim3(128, 8), 256, 0, stream>>>(G, XTK, VT);
        wtrans3<<<dim3(16, 8), 256, 0, stream>>>(dc_fw, WB, 64);
        mix_v2<<<dim3(64, 8), 256, 0, stream>>>(VT, WB, Yp, 64);
        idft_v2<<<dim3(2, 512), 256, 0, stream>>>(Yp, TibD, Tidb, 144, 128, 64,
                                                  1.f / (144.f * 262144.f));
        gemm(Tidb, dc_ow_b, dc_ob, nullptr, To_b, 18432, 512, 512, 512, 512, 0, 0);
        decomp_kernel<<<dim3(128, 8), 256, 0, stream>>>(
            XDb, To_b, XDb, TS, 144, 2);
    }

    // ---- decoder FFN: 2 chunks of N=1024; hid bf16 in SC, fout bf16 in XE area
    {
        unsigned short* hid = (unsigned short*)(SC);
        unsigned short* fout_b = (unsigned short*)XE;  // XE fp32 area is scratch
        for (int j0 = 0; j0 < 2048; j0 += 1024) {
            gemm(XDb, dec_c1_b + (size_t)j0 * 512, nullptr, nullptr, hid,
                 18432, 1024, 512, 512, 512, 1, 0);
            gemm(hid, dec_c2_b + j0, nullptr, nullptr, fout_b,
                 18432, 512, 1024, 1024, 2048, 0, j0 > 0);
        }
        decomp_kernel<<<dim3(128, 8), 256, 0, stream>>>(
            XDb, fout_b, XDb, TS, 144, 2);
    }

    // ---- final norm + trend conv + projection
    ln_rows_kernel<<<18432, 256, 0, stream>>>(XDb, dec_norm_w, dec_norm_b, XDb);
    timesub_kernel<<<dim3(128, 8), 256, 0, stream>>>(XDb, 144);
    final_v2<<<12288, 256, 0, stream>>>(
        XDb, TS, TI, dec_trend_w, proj_w, proj_b, (float*)d_out);
}